// Round 22
// baseline (252.899 us; speedup 1.0000x reference)
//
#include <hip/hip_runtime.h>
#include <hip/hip_bf16.h>
#include <math.h>

#define TT  100
#define CIN 400
#define H1  256
#define NS  32
#define NP  96
#define H3  512
#define H2C 128
#define BB  2
#define IJ  10000
#define NVALID 5050
#define NINVAL 4950
#define PADW 102
#define PPIX 10432
#define PSTRIDE (PPIX * H2C)

typedef __attribute__((ext_vector_type(8))) short bf16x8;
typedef __attribute__((ext_vector_type(4))) float f32x4;

// ---- static scratch (float units) ----
#define OFF_XT   0
#define OFF_H1   80000
#define OFF_H2   131200
#define OFF_SB   182400
#define OFF_EB   233600
#define OFF_PF   284800
#define OFF_ATB  336000      // bf16 pairs ATb[b][16 og32][3200 m][8 quad-rotated][4ch][2]
#define OFF_P1   8732800
#define OFF_P2   10068096
#define OFF_CINV 11403392    // uint[64]: c_inv as bf16 pairs
#define OFF_WQ1B 12683392
#define OFF_WQ2B 12716160
#define OFF_WQ3B 12789888
#define OFF_DESC 12863616    // u32 [96][5056] valid-rank indexed
#define OFF_PFT  13846656    // bf16 [b][112][256]
#define OFF_W3B  13875328    // bf16 [n][o][c]
#define OFF_PART 15972480    // bf16 [(b*2+half)][5056 v][512 ch]
#define G_TOTAL  21149824

__device__ __align__(16) float g_buf[G_TOTAL];

__device__ inline unsigned short f2bf(float f) {
    __hip_bfloat16 h = __float2bfloat16(f);
    return *(unsigned short*)&h;
}
__device__ inline float bf2f(unsigned short u) {
    union { unsigned int i; float f; } v; v.i = ((unsigned int)u) << 16; return v.f;
}
__device__ inline void dot2(float& acc, unsigned int a, unsigned int w) {
    asm("v_dot2_f32_bf16 %0, %1, %2, %0" : "+v"(acc) : "v"(a), "v"(w));
}
// async global->LDS, 16B per lane; lds dest = wave-uniform base + lane*16
__device__ inline void gload_lds16(const void* g, void* l) {
    __builtin_amdgcn_global_load_lds(
        (const __attribute__((address_space(1))) unsigned int*)g,
        (__attribute__((address_space(3))) unsigned int*)l, 16, 0, 0);
}

// ---------- merged prep: w3prep blocks [0,512) + element-wise prep ----------
#define PREP_IDS (65536 + 147456 + 147456 + 51712 + 5056 + BB * TT * CIN + BB * 12 * 256 + 128)
__global__ __launch_bounds__(256) void k_prepw(
        const float* __restrict__ wq1, const float* __restrict__ wq2,
        const float* __restrict__ wq3, const float* __restrict__ x,
        const float* __restrict__ b3d, const float* __restrict__ bq1,
        const float* __restrict__ w3d) {
    __shared__ float tile[8192];
    int tid = threadIdx.x;
    if (blockIdx.x < 512) {   // w3b[n][o][c] bf16 from w3d[o][c][n]
        int o = blockIdx.x;
        const float* src = w3d + o * 8192;
        for (int idx = tid; idx < 8192; idx += 256) tile[idx] = src[idx];
        __syncthreads();
        int n = tid & 31, ch = tid >> 5;
        unsigned short* w3b = (unsigned short*)(g_buf + OFF_W3B);
        unsigned int w[16];
        #pragma unroll
        for (int c2 = 0; c2 < 16; ++c2) {
            int c = ch * 32 + c2 * 2;
            w[c2] = (unsigned int)f2bf(tile[c * 32 + n]) |
                    ((unsigned int)f2bf(tile[(c + 1) * 32 + n]) << 16);
        }
        uint4* dst = (uint4*)(w3b + ((size_t)n * 512 + o) * 256 + ch * 32);
        dst[0] = make_uint4(w[0], w[1], w[2], w[3]);
        dst[1] = make_uint4(w[4], w[5], w[6], w[7]);
        dst[2] = make_uint4(w[8], w[9], w[10], w[11]);
        dst[3] = make_uint4(w[12], w[13], w[14], w[15]);
        return;
    }
    int id = (blockIdx.x - 512) * 256 + tid;
    if (id < 65536) {
        ((unsigned short*)(g_buf + OFF_WQ1B))[id] = f2bf(wq1[id]);
        return;
    }
    id -= 65536;
    if (id < 147456) {
        int q = id / 1152, k = id % 1152, tap = k >> 7, c = k & 127;
        ((unsigned short*)(g_buf + OFF_WQ2B))[id] = f2bf(wq2[(q * 128 + c) * 9 + tap]);
        return;
    }
    id -= 147456;
    if (id < 147456) {
        int q = id / 1152, k = id % 1152, tap = k >> 7, c = k & 127;
        ((unsigned short*)(g_buf + OFF_WQ3B))[id] = f2bf(wq3[(q * 128 + c) * 9 + tap]);
        return;
    }
    id -= 147456;
    if (id < 51712) {   // halo zero
        int c = id & 31;
        int h = (id >> 5) % 404;
        int bb = ((id >> 5) / 404) & 1;
        int buf = id / 25856;
        int pix;
        if (h < 102) pix = h;
        else if (h < 204) pix = 101 * PADW + (h - 102);
        else { int q = h - 204; pix = (1 + (q >> 1)) * PADW + ((q & 1) ? 101 : 0); }
        unsigned short* P = (unsigned short*)(g_buf + (buf ? OFF_P2 : OFF_P1))
                            + (size_t)bb * PSTRIDE + (size_t)pix * H2C;
        ((uint2*)P)[c] = make_uint2(0u, 0u);
        return;
    }
    id -= 51712;
    if (id < 5056) {   // desc: one thread per rank v, loop over all k
        int v = id;
        bool valid = (v < NVALID);
        double xmn = 0.0, plen = 0.0;
        if (valid) {
            int i = (int)(100.5 - sqrt(10100.25 - 2.0 * (double)v));
            if (i < 0) i = 0; if (i > 99) i = 99;
            while (100 * (i + 1) - ((i + 1) * i) / 2 <= v && i < 99) ++i;
            while (100 * i - (i * (i - 1)) / 2 > v && i > 0) --i;
            int j = i + (v - (100 * i - (i * (i - 1)) / 2));
            double len = (double)(j - i + 2);
            xmn = (double)i - 0.5 * len;
            double xmx = (double)(j + 1) + 0.5 * len;
            plen = (xmx - xmn) / 95.0;
        }
        unsigned int* dout = (unsigned int*)(g_buf + OFF_DESC);
        for (int k = 0; k < NP; ++k) {
            unsigned int nb = (unsigned int)((k / 3) * 100);
            unsigned int d = nb | (2u << 12);
            if (valid) {
                double s = __dadd_rn(xmn, __dmul_rn(plen, (double)k));
                double tr = trunc(s);
                double dec = s - tr;
                int dn = (int)tr;
                int up = (int)ceil(s);
                bool okd = (unsigned)dn < (unsigned)TT;
                bool oku = (unsigned)up < (unsigned)TT;
                if (!okd) d = nb | (2u << 12);
                else if (oku && up == dn + 1) {
                    unsigned int dfx = (unsigned int)__double2int_rn(dec * 65535.0);
                    d = (nb + dn) | (dfx << 16);
                } else if (oku) {
                    d = (nb + dn) | (1u << 12);
                } else {
                    unsigned int dfx = (unsigned int)__double2int_rn(dec * 65535.0);
                    d = (nb + dn) | (1u << 12) | (dfx << 16);
                }
            }
            dout[(size_t)k * 5056 + v] = d;
        }
        return;
    }
    id -= 5056;
    if (id < BB * TT * CIN) {   // x transpose
        int c = id % CIN, t = (id / CIN) % TT, b = id / (CIN * TT);
        g_buf[OFF_XT + (b * CIN + c) * TT + t] = x[id];
        return;
    }
    id -= BB * TT * CIN;
    if (id < BB * 12 * 256) {   // zero pfT pad rows
        int c = id & 255, tp = (id >> 8) % 12, b = id / (12 * 256);
        ((unsigned short*)(g_buf + OFF_PFT))[((size_t)b * 112 + 100 + tp) * 256 + c] = 0;
        return;
    }
    id -= BB * 12 * 256;
    if (id < 128) {   // c_inv[q] = relu(wq1 . relu(b3d) + bq1)
        int q = id;
        float acc = bq1[q];
        const float* wr = wq1 + q * 512;
        #pragma unroll 8
        for (int c = 0; c < 512; ++c) acc = fmaf(wr[c], fmaxf(b3d[c], 0.f), acc);
        acc = fmaxf(acc, 0.f);
        float accO = __shfl_xor(acc, 1);
        if ((id & 1) == 0)
            ((unsigned int*)(g_buf + OFF_CINV))[id >> 1] =
                (unsigned int)f2bf(acc) | ((unsigned int)f2bf(accO) << 16);
    }
}

// ---------- conv1d k=3 pad=1 + relu, split-4 over ci + shfl butterfly ----------
template<int IPG, int OPG, int CINTOT>
__global__ void k_conv_t(int in_off, const float* __restrict__ w,
                         const float* __restrict__ bias, int out_off) {
    int id = blockIdx.x * 256 + threadIdx.x;     // 4 lanes per output
    if (id >= 4 * BB * H1 * TT) return;
    int qh = id & 3, outp = id >> 2;
    int t = outp % TT, o = (outp / TT) % H1, b = outp / (TT * H1);
    const float* ip = g_buf + in_off
                    + (b * CINTOT + (o / OPG) * IPG + qh * (IPG / 4)) * TT + t;
    const float* wp = w + o * IPG * 3 + qh * (IPG / 4) * 3;
    float a0 = 0.f, a1 = 0.f, a2 = 0.f;
    bool t0 = (t > 0), t1 = (t < TT - 1);
    #pragma unroll 4
    for (int ci = 0; ci < IPG / 4; ++ci) {
        float v0 = t0 ? ip[ci * TT - 1] : 0.f;
        float v1 = ip[ci * TT];
        float v2 = t1 ? ip[ci * TT + 1] : 0.f;
        a0 = fmaf(v0, wp[ci * 3 + 0], a0);
        a1 = fmaf(v1, wp[ci * 3 + 1], a1);
        a2 = fmaf(v2, wp[ci * 3 + 2], a2);
    }
    float a = a0 + a1 + a2;
    a += __shfl_xor(a, 1);
    a += __shfl_xor(a, 2);
    if (qh == 0) g_buf[out_off + outp] = fmaxf(a + bias[o], 0.f);
}

// ---------- merged s/e convs + pf conv, split-4 ----------
__global__ void k_sepf(const float* __restrict__ ws1, const float* __restrict__ bs1,
                       const float* __restrict__ we1, const float* __restrict__ be1,
                       const float* __restrict__ wp, const float* __restrict__ bp) {
    int blk = blockIdx.x;
    if (blk < 1600) {   // s (0-799) / e (800-1599), grouped 64-ch, 16 ci per lane
        int sec = blk >= 800;
        int id = (blk - sec * 800) * 256 + threadIdx.x;
        if (id >= 4 * BB * H1 * TT) return;
        int qh = id & 3, outp = id >> 2;
        const float* w  = sec ? we1 : ws1;
        const float* bi = sec ? be1 : bs1;
        int out_off = sec ? OFF_EB : OFF_SB;
        int t = outp % TT, o = (outp / TT) % H1, b = outp / (TT * H1);
        const float* ip = g_buf + OFF_H2 + (b * H1 + (o / 64) * 64 + qh * 16) * TT + t;
        const float* wpp = w + o * 64 * 3 + qh * 16 * 3;
        float a0 = 0.f, a1 = 0.f, a2 = 0.f;
        bool tl = (t > 0), th = (t < TT - 1);
        #pragma unroll 4
        for (int ci = 0; ci < 16; ++ci) {
            float v0 = tl ? ip[ci * TT - 1] : 0.f;
            float v1 = ip[ci * TT];
            float v2 = th ? ip[ci * TT + 1] : 0.f;
            a0 = fmaf(v0, wpp[ci * 3 + 0], a0);
            a1 = fmaf(v1, wpp[ci * 3 + 1], a1);
            a2 = fmaf(v2, wpp[ci * 3 + 2], a2);
        }
        float a = a0 + a1 + a2;
        a += __shfl_xor(a, 1);
        a += __shfl_xor(a, 2);
        if (qh == 0) g_buf[out_off + outp] = fmaxf(a + bi[o], 0.f);
    } else {            // pf conv (256 ch) -> pfT bf16, 64 ci per lane
        int id = (blk - 1600) * 256 + threadIdx.x;
        if (id >= 4 * BB * H1 * TT) return;
        int qh = id & 3, outp = id >> 2;
        int t = outp % TT, o = (outp / TT) % H1, b = outp / (TT * H1);
        const float* ip = g_buf + OFF_H2 + (b * H1 + qh * 64) * TT + t;
        const float* wpp = wp + o * H1 * 3 + qh * 64 * 3;
        float a0 = 0.f, a1 = 0.f, a2 = 0.f;
        bool tl = (t > 0), th = (t < TT - 1);
        #pragma unroll 4
        for (int ci = 0; ci < 64; ++ci) {
            float v0 = tl ? ip[ci * TT - 1] : 0.f;
            float v1 = ip[ci * TT];
            float v2 = th ? ip[ci * TT + 1] : 0.f;
            a0 = fmaf(v0, wpp[ci * 3 + 0], a0);
            a1 = fmaf(v1, wpp[ci * 3 + 1], a1);
            a2 = fmaf(v2, wpp[ci * 3 + 2], a2);
        }
        float a = a0 + a1 + a2;
        a += __shfl_xor(a, 1);
        a += __shfl_xor(a, 2);
        if (qh == 0)
            ((unsigned short*)(g_buf + OFF_PFT))[((size_t)b * 112 + t) * 256 + o] =
                f2bf(fmaxf(a + bp[o], 0.f));
    }
}

// ---------- merged: Am (MFMA A-build, quad-rotated layout) + q1f + heads ----------
#define Q1F_BLKS ((BB * NINVAL * 16 + 255) / 256)
__global__ __launch_bounds__(256) void k_amfh(
        const float* __restrict__ ws2, const float* __restrict__ bs2,
        const float* __restrict__ we2, const float* __restrict__ be2,
        float* __restrict__ out) {
    int blk = blockIdx.x;
    if (blk < 1792) {   // k_Am: ATb pairs, quad-rotated: ch c of row m at quad ((c>>2)+m)&7
        int mt = blk % 7, nt = (blk / 7) % 4, bn = blk / 28;
        int b = bn >> 5, n = bn & 31;
        int wv = threadIdx.x >> 6, lane = threadIdx.x & 63;
        int r = lane & 15, g = lane >> 4;
        const unsigned short* ap = (const unsigned short*)(g_buf + OFF_PFT)
                                   + ((size_t)b * 112 + mt * 16 + r) * 256 + g * 8;
        const unsigned short* bp = (const unsigned short*)(g_buf + OFF_W3B)
                                   + ((size_t)n * 512 + nt * 128 + wv * 32 + r) * 256 + g * 8;
        f32x4 acc0 = {0.f, 0.f, 0.f, 0.f}, acc1 = {0.f, 0.f, 0.f, 0.f};
        #pragma unroll
        for (int ks = 0; ks < 8; ++ks) {
            bf16x8 a  = *(const bf16x8*)(ap + ks * 32);
            bf16x8 b0 = *(const bf16x8*)(bp + ks * 32);
            bf16x8 b1 = *(const bf16x8*)(bp + 16 * 256 + ks * 32);
            acc0 = __builtin_amdgcn_mfma_f32_16x16x32_bf16(a, b0, acc0, 0, 0, 0);
            acc1 = __builtin_amdgcn_mfma_f32_16x16x32_bf16(a, b1, acc1, 0, 0, 0);
        }
        unsigned short* ATb = (unsigned short*)(g_buf + OFF_ATB);
        int og = nt * 4 + wv;
        size_t gb = (size_t)(b * 16 + og) * 3200;
        int c0 = r, c1 = 16 + r;
        int q0c = c0 >> 2, o0c = (c0 & 3) * 2;
        int q1c = c1 >> 2, o1c = (c1 & 3) * 2;
        #pragma unroll
        for (int reg = 0; reg < 4; ++reg) {
            int t = mt * 16 + g * 4 + reg;
            if (t < TT) {
                int m = n * 100 + t;
                unsigned short v0 = f2bf(acc0[reg] * (1.f / 3.f));
                unsigned short v1 = f2bf(acc1[reg] * (1.f / 3.f));
                size_t row = (gb + m) * 64;
                size_t base0 = row + (size_t)((((q0c + m) & 7) << 3) + o0c);
                size_t base1 = row + (size_t)((((q1c + m) & 7) << 3) + o1c);
                ATb[base0] = v0;
                ATb[base1] = v1;
                if (t > 0) {
                    size_t rowp = (gb + m - 1) * 64;
                    ATb[rowp + (size_t)((((q0c + m - 1) & 7) << 3) + o0c) + 1] = v0;
                    ATb[rowp + (size_t)((((q1c + m - 1) & 7) << 3) + o1c) + 1] = v1;
                }
                if (t == TT - 1) {
                    ATb[base0 + 1] = 0;
                    ATb[base1 + 1] = 0;
                }
            }
        }
        return;
    }
    if (blk < 1792 + Q1F_BLKS) {   // q1f: invalid (i>j) pixels only, rank-indexed
        int id = (blk - 1792) * 256 + threadIdx.x;
        if (id >= BB * NINVAL * 16) return;
        int c = id & 15;
        int rr = (id >> 4) % NINVAL;
        int b = id / (16 * NINVAL);
        int i = (int)((1.0 + sqrt(1.0 + 8.0 * (double)rr)) * 0.5);
        if (i < 1) i = 1; if (i > 99) i = 99;
        while ((i * (i - 1)) / 2 > rr) --i;
        while (((i + 1) * i) / 2 <= rr) ++i;
        int j = rr - (i * (i - 1)) / 2;        // j in [0, i) => i > j
        uint4 w = ((const uint4*)(g_buf + OFF_CINV))[c];
        unsigned short* P1 = (unsigned short*)(g_buf + OFF_P1) + (size_t)b * PSTRIDE;
        *(uint4*)(P1 + (size_t)((i + 1) * PADW + j + 1) * H2C + c * 8) = w;
        return;
    }
    {   // heads
        int which = blk - (1792 + Q1F_BLKS);
        const float* w  = which ? we2 : ws2;
        const float* bi = which ? be2 : bs2;
        int in_off = which ? OFF_EB : OFF_SB;
        int id = threadIdx.x;
        if (id >= BB * TT) return;
        int t = id % TT, b = id / TT;
        const float* ip = g_buf + in_off + b * H1 * TT + t;
        float acc = bi[0];
        for (int c = 0; c < H1; ++c) acc = fmaf(ip[c * TT], w[c], acc);
        out[40000 + which * 200 + id] = 1.f / (1.f + expf(-acc));
    }
}

// ---------- BM gather: 32 ch/block, k-split x2, bf16 partials, async LDS stage ----------
__global__ __launch_bounds__(256) void k_bm2() {
    __shared__ uint4 Ash[1600];                 // 200 rows x 8 quads (rotation baked in global)
    int qt = blockIdx.x, og = blockIdx.y, z = blockIdx.z;
    int b = z >> 1, half = z & 1;
    int tid = threadIdx.x;
    int lane = tid & 63, wv4 = tid >> 6;
    int v = qt * 256 + tid;
    bool val = (v < NVALID);
    int vv = val ? v : 0;
    const unsigned int* desc = (const unsigned int*)(g_buf + OFF_DESC);
    const uint4* src = (const uint4*)((const unsigned short*)(g_buf + OFF_ATB)
                                      + (size_t)(b * 16 + og) * 3200 * 64);
    float acc[32];
    #pragma unroll
    for (int c = 0; c < 32; ++c) acc[c] = 0.f;

    for (int st = half * 8; st < half * 8 + 8; ++st) {
        __syncthreads();
        for (int idx0 = wv4 * 64; idx0 < 1600; idx0 += 256)
            gload_lds16(src + st * 1600 + idx0 + lane, (void*)&Ash[idx0]);
        __syncthreads();
        #pragma unroll
        for (int kk = 0; kk < 6; ++kk) {
            unsigned int d = desc[(size_t)(st * 6 + kk) * 5056 + vv];
            int t2 = (int)(d & 0xFFFu) - st * 200;
            unsigned int mode = (d >> 12) & 3u;
            float dec = (float)(d >> 16) * (1.f / 65535.f);
            float w0 = (mode == 2u) ? 0.f : 1.f - dec;
            float w1 = (mode == 0u) ? dec : 0.f;
            unsigned int wpair;
            asm("v_cvt_pk_bf16_f32 %0, %1, %2" : "=v"(wpair) : "v"(w0), "v"(w1));
            int base = t2 << 3;
            uint4 A0 = Ash[base | ((0 + t2) & 7)];
            uint4 A1 = Ash[base | ((1 + t2) & 7)];
            uint4 A2 = Ash[base | ((2 + t2) & 7)];
            uint4 A3 = Ash[base | ((3 + t2) & 7)];
            uint4 A4 = Ash[base | ((4 + t2) & 7)];
            uint4 A5 = Ash[base | ((5 + t2) & 7)];
            uint4 A6 = Ash[base | ((6 + t2) & 7)];
            uint4 A7 = Ash[base | ((7 + t2) & 7)];
            dot2(acc[0],  A0.x, wpair); dot2(acc[1],  A0.y, wpair);
            dot2(acc[2],  A0.z, wpair); dot2(acc[3],  A0.w, wpair);
            dot2(acc[4],  A1.x, wpair); dot2(acc[5],  A1.y, wpair);
            dot2(acc[6],  A1.z, wpair); dot2(acc[7],  A1.w, wpair);
            dot2(acc[8],  A2.x, wpair); dot2(acc[9],  A2.y, wpair);
            dot2(acc[10], A2.z, wpair); dot2(acc[11], A2.w, wpair);
            dot2(acc[12], A3.x, wpair); dot2(acc[13], A3.y, wpair);
            dot2(acc[14], A3.z, wpair); dot2(acc[15], A3.w, wpair);
            dot2(acc[16], A4.x, wpair); dot2(acc[17], A4.y, wpair);
            dot2(acc[18], A4.z, wpair); dot2(acc[19], A4.w, wpair);
            dot2(acc[20], A5.x, wpair); dot2(acc[21], A5.y, wpair);
            dot2(acc[22], A5.z, wpair); dot2(acc[23], A5.w, wpair);
            dot2(acc[24], A6.x, wpair); dot2(acc[25], A6.y, wpair);
            dot2(acc[26], A6.z, wpair); dot2(acc[27], A6.w, wpair);
            dot2(acc[28], A7.x, wpair); dot2(acc[29], A7.y, wpair);
            dot2(acc[30], A7.z, wpair); dot2(acc[31], A7.w, wpair);
        }
    }
    if (val) {
        unsigned short* PB = (unsigned short*)(g_buf + OFF_PART)
                             + ((size_t)(b * 2 + half) * 5056 + v) * 512 + og * 32;
        unsigned int w[16];
        #pragma unroll
        for (int c2 = 0; c2 < 16; ++c2)
            w[c2] = (unsigned int)f2bf(acc[c2 * 2]) |
                    ((unsigned int)f2bf(acc[c2 * 2 + 1]) << 16);
        uint4* dst = (uint4*)PB;
        dst[0] = make_uint4(w[0],  w[1],  w[2],  w[3]);
        dst[1] = make_uint4(w[4],  w[5],  w[6],  w[7]);
        dst[2] = make_uint4(w[8],  w[9],  w[10], w[11]);
        dst[3] = make_uint4(w[12], w[13], w[14], w[15]);
    }
}

#define MFMA16(a, b, c) __builtin_amdgcn_mfma_f32_16x16x32_bf16(a, b, c, 0, 0, 0)

// ---------- q1: valid pixels only; fuses bf16-partial combine + bias + relu ----------
__global__ __launch_bounds__(256) void k_q1m(const float* __restrict__ bias,
                                             const float* __restrict__ b3d) {
    __shared__ uint4 As[2048];
    __shared__ int qmap[32];
    const unsigned short* Bw = (const unsigned short*)(g_buf + OFF_WQ1B);
    unsigned short* P1 = (unsigned short*)(g_buf + OFF_P1);
    int m0 = blockIdx.x * 32, b = blockIdx.y;
    int tid = threadIdx.x;
    if (tid < 32) {
        int v = m0 + tid; if (v >= NVALID) v = NVALID - 1;
        int i = (int)(100.5 - sqrt(10100.25 - 2.0 * (double)v));
        if (i < 0) i = 0; if (i > 99) i = 99;
        while (100 * (i + 1) - ((i + 1) * i) / 2 <= v && i < 99) ++i;
        while (100 * i - (i * (i - 1)) / 2 > v && i > 0) --i;
        int j = i + (v - (100 * i - (i * (i - 1)) / 2));
        qmap[tid] = i * 100 + j;
    }
    __syncthreads();
    const unsigned short* PB = (const unsigned short*)(g_buf + OFF_PART);
    const size_t PSET = (size_t)5056 * 512;    // ush per partial set
    for (int idx = tid; idx < 2048; idx += 256) {
        int px = idx >> 6, ch = idx & 63;      // ch = octet of channels
        int vr = m0 + px; if (vr >= NVALID) vr = NVALID - 1;
        size_t base = ((size_t)(b * 2) * 5056 + vr) * 512 + ch * 8;
        uint4 s4 = *(const uint4*)(PB + base);
        uint4 t4 = *(const uint4*)(PB + base + PSET);
        const float* bb = b3d + ch * 8;
        unsigned int su[4] = {s4.x, s4.y, s4.z, s4.w};
        unsigned int tu[4] = {t4.x, t4.y, t4.z, t4.w};
        unsigned int w[4];
        #pragma unroll
        for (int wd = 0; wd < 4; ++wd) {
            float x0 = fmaxf(bf2f((unsigned short)su[wd]) +
                             bf2f((unsigned short)tu[wd]) + bb[wd * 2], 0.f);
            float x1 = fmaxf(bf2f((unsigned short)(su[wd] >> 16)) +
                             bf2f((unsigned short)(tu[wd] >> 16)) + bb[wd * 2 + 1], 0.f);
            w[wd] = (unsigned int)f2bf(x0) | ((unsigned int)f2bf(x1) << 16);
        }
        int ch2 = ch ^ (px & 7) ^ (((px >> 3) & 1) << 3);
        As[px * 64 + ch2] = make_uint4(w[0], w[1], w[2], w[3]);
    }
    __syncthreads();
    int wv = tid >> 6, lane = tid & 63, r = lane & 15, g = lane >> 4;
    int q0 = wv * 32;
    f32x4 acc[2][2] = {{{0.f,0.f,0.f,0.f},{0.f,0.f,0.f,0.f}},{{0.f,0.f,0.f,0.f},{0.f,0.f,0.f,0.f}}};
    bf16x8 Bb[4][2], Aa[2][2];
#define Q1_LB(slot, it_) { const unsigned short* bp = Bw + (size_t)(q0 + r) * 512 + (it_) * 32 + g * 8; \
    Bb[slot][0] = *(const bf16x8*)bp; Bb[slot][1] = *(const bf16x8*)(bp + 16 * 512); }
#define Q1_LA(slot, it_) { int ch = (it_) * 4 + g; \
    int px0 = r, px1 = 16 + r; \
    Aa[slot][0] = *(const bf16x8*)&As[px0 * 64 + (ch ^ (px0 & 7) ^ (((px0 >> 3) & 1) << 3))]; \
    Aa[slot][1] = *(const bf16x8*)&As[px1 * 64 + (ch ^ (px1 & 7) ^ (((px1 >> 3) & 1) << 3))]; }
    Q1_LB(0, 0); Q1_LB(1, 1); Q1_LB(2, 2); Q1_LA(0, 0);
    #pragma unroll
    for (int it = 0; it < 16; ++it) {
        if (it + 3 < 16) Q1_LB((it + 3) & 3, it + 3);
        if (it + 1 < 16) Q1_LA((it + 1) & 1, it + 1);
        int s = it & 3, sa = it & 1;
        acc[0][0] = MFMA16(Aa[sa][0], Bb[s][0], acc[0][0]);
        acc[0][1] = MFMA16(Aa[sa][0], Bb[s][1], acc[0][1]);
        acc[1][0] = MFMA16(Aa[sa][1], Bb[s][0], acc[1][0]);
        acc[1][1] = MFMA16(Aa[sa][1], Bb[s][1], acc[1][1]);
    }
    float bi0 = bias[q0 + r], bi1 = bias[q0 + 16 + r];
    unsigned short* Pout = P1 + (size_t)b * PSTRIDE;
    #pragma unroll
    for (int mt = 0; mt < 2; ++mt)
        #pragma unroll
        for (int reg = 0; reg < 4; ++reg) {
            int px = mt * 16 + g * 4 + reg;
            if (m0 + px < NVALID) {
                int q = qmap[px];
                int i = q / 100, j = q - i * 100;
                size_t base = (size_t)((i + 1) * PADW + j + 1) * H2C;
                Pout[base + q0 + r]      = f2bf(fmaxf(acc[mt][0][reg] + bi0, 0.f));
                Pout[base + q0 + 16 + r] = f2bf(fmaxf(acc[mt][1][reg] + bi1, 0.f));
            }
        }
}

// ---------- 3x3 conv 128->128, M=64 (2 output rows/block); FQ4: fused q4+sigmoid ----------
template<int FQ4>
__global__ __launch_bounds__(256) void k_c3m2(int in_off, int w_off,
                                              const float* __restrict__ bias,
                                              int out_off,
                                              const float* __restrict__ wq4,
                                              const float* __restrict__ bq4,
                                              float* __restrict__ out) {
    __shared__ uint4 As[2176];                 // 4 rows x 34 px x 16 oct
    const unsigned short* Pin = (const unsigned short*)(g_buf + in_off);
    const unsigned short* wB  = (const unsigned short*)(g_buf + w_off);
    int jt = blockIdx.x, y = blockIdx.y, b = blockIdx.z;
    int i0 = y * 2;
    int j0 = (jt == 3) ? 68 : jt * 32;
    int tid = threadIdx.x;
    const unsigned short* Ab = Pin + (size_t)b * PSTRIDE;
    for (int idx = tid; idx < 2176; idx += 256) {
        int row = idx / 544, rem = idx - row * 544;
        int px = rem >> 4, ch = rem & 15;
        int ch2 = ch ^ (px & 7) ^ (((px >> 3) & 1) << 3);
        As[(row * 34 + px) * 16 + ch2] =
            *(const uint4*)(Ab + (size_t)((i0 + row) * PADW + j0 + px) * H2C + ch * 8);
    }
    __syncthreads();
    int wv = tid >> 6, lane = tid & 63, r = lane & 15, g = lane >> 4;
    int q0 = wv * 32;
    f32x4 acc[2][2][2];
    #pragma unroll
    for (int a = 0; a < 2; ++a)
        #pragma unroll
        for (int m = 0; m < 2; ++m)
            #pragma unroll
            for (int h = 0; h < 2; ++h) acc[a][m][h] = (f32x4){0.f, 0.f, 0.f, 0.f};
    bf16x8 Bb[4][2], Aa[2][4];
#define C2_LB(slot, it_) { int tap = (it_) >> 2, cc = (it_) & 3; \
    const unsigned short* bp = wB + (size_t)(q0 + r) * 1152 + tap * 128 + cc * 32 + g * 8; \
    Bb[slot][0] = *(const bf16x8*)bp; Bb[slot][1] = *(const bf16x8*)(bp + 16 * 1152); }
#define C2_LA(slot, it_) { int tap = (it_) >> 2, cc = (it_) & 3; \
    int ky = tap / 3, kx = tap - ky * 3; int ch = cc * 4 + g; \
    int px0 = r + kx, px1 = 16 + r + kx; \
    Aa[slot][0] = *(const bf16x8*)&As[(ky * 34 + px0) * 16 + (ch ^ (px0 & 7) ^ (((px0 >> 3) & 1) << 3))]; \
    Aa[slot][1] = *(const bf16x8*)&As[(ky * 34 + px1) * 16 + (ch ^ (px1 & 7) ^ (((px1 >> 3) & 1) << 3))]; \
    Aa[slot][2] = *(const bf16x8*)&As[((ky + 1) * 34 + px0) * 16 + (ch ^ (px0 & 7) ^ (((px0 >> 3) & 1) << 3))]; \
    Aa[slot][3] = *(const bf16x8*)&As[((ky + 1) * 34 + px1) * 16 + (ch ^ (px1 & 7) ^ (((px1 >> 3) & 1) << 3))]; }
    C2_LB(0, 0); C2_LB(1, 1); C2_LB(2, 2); C2_LA(0, 0);
    #pragma unroll
    for (int it = 0; it < 36; ++it) {
        if (it + 3 < 36) C2_LB((it + 3) & 3, it + 3);
        if (it + 1 < 36) C2_LA((it + 1) & 1, it + 1);
        int s = it & 3, sa = it & 1;
        acc[0][0][0] = MFMA16(Aa[sa][0], Bb[s][0], acc[0][0][0]);
        acc[0][0][1] = MFMA16(Aa[sa][0], Bb[s][1], acc[0][0][1]);
        acc[0][1][0] = MFMA16(Aa[sa][1], Bb[s][0], acc[0][1][0]);
        acc[0][1][1] = MFMA16(Aa[sa][1], Bb[s][1], acc[0][1][1]);
        acc[1][0][0] = MFMA16(Aa[sa][2], Bb[s][0], acc[1][0][0]);
        acc[1][0][1] = MFMA16(Aa[sa][2], Bb[s][1], acc[1][0][1]);
        acc[1][1][0] = MFMA16(Aa[sa][3], Bb[s][0], acc[1][1][0]);
        acc[1][1][1] = MFMA16(Aa[sa][3], Bb[s][1], acc[1][1][1]);
    }
    float bi0 = bias[q0 + r], bi1 = bias[q0 + 16 + r];
    if constexpr (!FQ4) {
        unsigned short* Ob = (unsigned short*)(g_buf + out_off) + (size_t)b * PSTRIDE;
        #pragma unroll
        for (int orow = 0; orow < 2; ++orow)
            #pragma unroll
            for (int mt = 0; mt < 2; ++mt)
                #pragma unroll
                for (int reg = 0; reg < 4; ++reg) {
                    int j = j0 + mt * 16 + g * 4 + reg;
                    size_t base = (size_t)((i0 + orow + 1) * PADW + j + 1) * H2C;
                    Ob[base + q0 + r]      = f2bf(fmaxf(acc[orow][mt][0][reg] + bi0, 0.f));
                    Ob[base + q0 + 16 + r] = f2bf(fmaxf(acc[orow][mt][1][reg] + bi1, 0.f));
                }
    } else {
        __shared__ float part[4][2][2][32];
        float w40a = wq4[q0 + r],       w40b = wq4[q0 + 16 + r];
        float w41a = wq4[128 + q0 + r], w41b = wq4[128 + q0 + 16 + r];
        #pragma unroll
        for (int orow = 0; orow < 2; ++orow)
            #pragma unroll
            for (int mt = 0; mt < 2; ++mt)
                #pragma unroll
                for (int reg = 0; reg < 4; ++reg) {
                    float x0 = fmaxf(acc[orow][mt][0][reg] + bi0, 0.f);
                    float x1 = fmaxf(acc[orow][mt][1][reg] + bi1, 0.f);
                    float p0 = x0 * w40a + x1 * w40b;
                    float p1 = x0 * w41a + x1 * w41b;
                    #pragma unroll
                    for (int off = 1; off < 16; off <<= 1) {
                        p0 += __shfl_xor(p0, off);
                        p1 += __shfl_xor(p1, off);
                    }
                    if (r == 0) {
                        int px = mt * 16 + g * 4 + reg;
                        part[wv][orow][0][px] = p0;
                        part[wv][orow][1][px] = p1;
                    }
                }
        __syncthreads();
        if (tid < 128) {
            int px = tid & 31, hd = (tid >> 5) & 1, orow = tid >> 6;
            float s = part[0][orow][hd][px] + part[1][orow][hd][px] +
                      part[2][orow][hd][px] + part[3][orow][hd][px] + bq4[hd];
            out[(size_t)(b * 2 + hd) * IJ + (i0 + orow) * 100 + (j0 + px)] =
                1.f / (1.f + expf(-s));
        }
    }
}

extern "C" void kernel_launch(void* const* d_in, const int* in_sizes, int n_in,
                              void* d_out, int out_size, void* d_ws, size_t ws_size,
                              hipStream_t stream) {
    const float* x   = (const float*)d_in[0];
    const float* wb1 = (const float*)d_in[1];  const float* bb1 = (const float*)d_in[2];
    const float* wb2 = (const float*)d_in[3];  const float* bb2 = (const float*)d_in[4];
    const float* ws1 = (const float*)d_in[5];  const float* bs1 = (const float*)d_in[6];
    const float* ws2 = (const float*)d_in[7];  const float* bs2 = (const float*)d_in[8];
    const float* we1 = (const float*)d_in[9];  const float* be1 = (const float*)d_in[10];
    const float* we2 = (const float*)d_in[11]; const float* be2 = (const float*)d_in[12];
    const float* wp  = (const float*)d_in[13]; const float* bp  = (const float*)d_in[14];
    const float* w3d = (const float*)d_in[15]; const float* b3d = (const float*)d_in[16];
    const float* wq1 = (const float*)d_in[17]; const float* bq1 = (const float*)d_in[18];
    const float* wq2 = (const float*)d_in[19]; const float* bq2 = (const float*)d_in[20];
    const float* wq3 = (const float*)d_in[21]; const float* bq3 = (const float*)d_in[22];
    const float* wq4 = (const float*)d_in[23]; const float* bq4 = (const float*)d_in[24];
    float* out = (float*)d_out;

    k_prepw<<<512 + (PREP_IDS + 255) / 256, 256, 0, stream>>>(wq1, wq2, wq3, x, b3d, bq1, w3d);
    k_conv_t<100, 64, 400><<<800, 256, 0, stream>>>(OFF_XT, wb1, bb1, OFF_H1);
    k_conv_t<64, 64, 256><<<800, 256, 0, stream>>>(OFF_H1, wb2, bb2, OFF_H2);
    k_sepf<<<2400, 256, 0, stream>>>(ws1, bs1, we1, be1, wp, bp);
    k_amfh<<<1792 + Q1F_BLKS + 2, 256, 0, stream>>>(ws2, bs2, we2, be2, out);
    k_bm2<<<dim3(20, 16, 4), 256, 0, stream>>>();
    k_q1m<<<dim3((NVALID + 31) / 32, 2), 256, 0, stream>>>(bq1, b3d);
    k_c3m2<0><<<dim3(4, 50, 2), 256, 0, stream>>>(OFF_P1, OFF_WQ2B, bq2, OFF_P2,
                                                  nullptr, nullptr, nullptr);
    k_c3m2<1><<<dim3(4, 50, 2), 256, 0, stream>>>(OFF_P2, OFF_WQ3B, bq3, 0,
                                                  wq4, bq4, out);
}

// Round 23
// 220.303 us; speedup vs baseline: 1.1480x; 1.1480x over previous
//
#include <hip/hip_runtime.h>
#include <hip/hip_bf16.h>
#include <math.h>

#define TT  100
#define CIN 400
#define H1  256
#define NS  32
#define NP  96
#define H3  512
#define H2C 128
#define BB  2
#define IJ  10000
#define NVALID 5050
#define NINVAL 4950
#define PADW 102
#define PPIX 10432
#define PSTRIDE (PPIX * H2C)

typedef __attribute__((ext_vector_type(8))) short bf16x8;
typedef __attribute__((ext_vector_type(4))) float f32x4;

// ---- static scratch (float units) ----
#define OFF_XT   0
#define OFF_H1   80000
#define OFF_H2   131200
#define OFF_SB   182400
#define OFF_EB   233600
#define OFF_PF   284800
#define OFF_ATB  336000      // bf16 pairs ATb[b][16 og32][3200 m][8 quad-rotated][4ch][2]
#define OFF_P1   8732800
#define OFF_P2   10068096
#define OFF_CINV 11403392    // uint[64]: c_inv as bf16 pairs
#define OFF_WQ1B 12683392
#define OFF_WQ2B 12716160
#define OFF_WQ3B 12789888
#define OFF_DESC 12863616    // u32 [96][5056] valid-rank indexed
#define OFF_PFT  13846656    // bf16 [b][112][256]
#define OFF_W3B  13875328    // bf16 [n][o][c]
#define OFF_PART 15972480    // bf16 [(b*2+half)][5056 v][512 ch]
#define G_TOTAL  21149824

__device__ __align__(16) float g_buf[G_TOTAL];

__device__ inline unsigned short f2bf(float f) {
    __hip_bfloat16 h = __float2bfloat16(f);
    return *(unsigned short*)&h;
}
__device__ inline float bf2f(unsigned short u) {
    union { unsigned int i; float f; } v; v.i = ((unsigned int)u) << 16; return v.f;
}
__device__ inline void dot2(float& acc, unsigned int a, unsigned int w) {
    asm("v_dot2_f32_bf16 %0, %1, %2, %0" : "+v"(acc) : "v"(a), "v"(w));
}
// async global->LDS, 16B per lane; lds dest = wave-uniform base + lane*16
__device__ inline void gload_lds16(const void* g, void* l) {
    __builtin_amdgcn_global_load_lds(
        (const __attribute__((address_space(1))) unsigned int*)g,
        (__attribute__((address_space(3))) unsigned int*)l, 16, 0, 0);
}

// ---------- merged prep: w3prep blocks [0,512) + element-wise prep ----------
#define PREP_IDS (65536 + 147456 + 147456 + 51712 + 5056 + BB * TT * CIN + BB * 12 * 256 + 128)
__global__ __launch_bounds__(256) void k_prepw(
        const float* __restrict__ wq1, const float* __restrict__ wq2,
        const float* __restrict__ wq3, const float* __restrict__ x,
        const float* __restrict__ b3d, const float* __restrict__ bq1,
        const float* __restrict__ w3d) {
    __shared__ float tile[8192];
    int tid = threadIdx.x;
    if (blockIdx.x < 512) {   // w3b[n][o][c] bf16 from w3d[o][c][n]
        int o = blockIdx.x;
        const float* src = w3d + o * 8192;
        for (int idx = tid; idx < 8192; idx += 256) tile[idx] = src[idx];
        __syncthreads();
        int n = tid & 31, ch = tid >> 5;
        unsigned short* w3b = (unsigned short*)(g_buf + OFF_W3B);
        unsigned int w[16];
        #pragma unroll
        for (int c2 = 0; c2 < 16; ++c2) {
            int c = ch * 32 + c2 * 2;
            w[c2] = (unsigned int)f2bf(tile[c * 32 + n]) |
                    ((unsigned int)f2bf(tile[(c + 1) * 32 + n]) << 16);
        }
        uint4* dst = (uint4*)(w3b + ((size_t)n * 512 + o) * 256 + ch * 32);
        dst[0] = make_uint4(w[0], w[1], w[2], w[3]);
        dst[1] = make_uint4(w[4], w[5], w[6], w[7]);
        dst[2] = make_uint4(w[8], w[9], w[10], w[11]);
        dst[3] = make_uint4(w[12], w[13], w[14], w[15]);
        return;
    }
    int id = (blockIdx.x - 512) * 256 + tid;
    if (id < 65536) {
        ((unsigned short*)(g_buf + OFF_WQ1B))[id] = f2bf(wq1[id]);
        return;
    }
    id -= 65536;
    if (id < 147456) {
        int q = id / 1152, k = id % 1152, tap = k >> 7, c = k & 127;
        ((unsigned short*)(g_buf + OFF_WQ2B))[id] = f2bf(wq2[(q * 128 + c) * 9 + tap]);
        return;
    }
    id -= 147456;
    if (id < 147456) {
        int q = id / 1152, k = id % 1152, tap = k >> 7, c = k & 127;
        ((unsigned short*)(g_buf + OFF_WQ3B))[id] = f2bf(wq3[(q * 128 + c) * 9 + tap]);
        return;
    }
    id -= 147456;
    if (id < 51712) {   // halo zero
        int c = id & 31;
        int h = (id >> 5) % 404;
        int bb = ((id >> 5) / 404) & 1;
        int buf = id / 25856;
        int pix;
        if (h < 102) pix = h;
        else if (h < 204) pix = 101 * PADW + (h - 102);
        else { int q = h - 204; pix = (1 + (q >> 1)) * PADW + ((q & 1) ? 101 : 0); }
        unsigned short* P = (unsigned short*)(g_buf + (buf ? OFF_P2 : OFF_P1))
                            + (size_t)bb * PSTRIDE + (size_t)pix * H2C;
        ((uint2*)P)[c] = make_uint2(0u, 0u);
        return;
    }
    id -= 51712;
    if (id < 5056) {   // desc: one thread per rank v, loop over all k
        int v = id;
        bool valid = (v < NVALID);
        double xmn = 0.0, plen = 0.0;
        if (valid) {
            int i = (int)(100.5 - sqrt(10100.25 - 2.0 * (double)v));
            if (i < 0) i = 0; if (i > 99) i = 99;
            while (100 * (i + 1) - ((i + 1) * i) / 2 <= v && i < 99) ++i;
            while (100 * i - (i * (i - 1)) / 2 > v && i > 0) --i;
            int j = i + (v - (100 * i - (i * (i - 1)) / 2));
            double len = (double)(j - i + 2);
            xmn = (double)i - 0.5 * len;
            double xmx = (double)(j + 1) + 0.5 * len;
            plen = (xmx - xmn) / 95.0;
        }
        unsigned int* dout = (unsigned int*)(g_buf + OFF_DESC);
        for (int k = 0; k < NP; ++k) {
            unsigned int nb = (unsigned int)((k / 3) * 100);
            unsigned int d = nb | (2u << 12);
            if (valid) {
                double s = __dadd_rn(xmn, __dmul_rn(plen, (double)k));
                double tr = trunc(s);
                double dec = s - tr;
                int dn = (int)tr;
                int up = (int)ceil(s);
                bool okd = (unsigned)dn < (unsigned)TT;
                bool oku = (unsigned)up < (unsigned)TT;
                if (!okd) d = nb | (2u << 12);
                else if (oku && up == dn + 1) {
                    unsigned int dfx = (unsigned int)__double2int_rn(dec * 65535.0);
                    d = (nb + dn) | (dfx << 16);
                } else if (oku) {
                    d = (nb + dn) | (1u << 12);
                } else {
                    unsigned int dfx = (unsigned int)__double2int_rn(dec * 65535.0);
                    d = (nb + dn) | (1u << 12) | (dfx << 16);
                }
            }
            dout[(size_t)k * 5056 + v] = d;
        }
        return;
    }
    id -= 5056;
    if (id < BB * TT * CIN) {   // x transpose
        int c = id % CIN, t = (id / CIN) % TT, b = id / (CIN * TT);
        g_buf[OFF_XT + (b * CIN + c) * TT + t] = x[id];
        return;
    }
    id -= BB * TT * CIN;
    if (id < BB * 12 * 256) {   // zero pfT pad rows
        int c = id & 255, tp = (id >> 8) % 12, b = id / (12 * 256);
        ((unsigned short*)(g_buf + OFF_PFT))[((size_t)b * 112 + 100 + tp) * 256 + c] = 0;
        return;
    }
    id -= BB * 12 * 256;
    if (id < 128) {   // c_inv[q] = relu(wq1 . relu(b3d) + bq1)
        int q = id;
        float acc = bq1[q];
        const float* wr = wq1 + q * 512;
        #pragma unroll 8
        for (int c = 0; c < 512; ++c) acc = fmaf(wr[c], fmaxf(b3d[c], 0.f), acc);
        acc = fmaxf(acc, 0.f);
        float accO = __shfl_xor(acc, 1);
        if ((id & 1) == 0)
            ((unsigned int*)(g_buf + OFF_CINV))[id >> 1] =
                (unsigned int)f2bf(acc) | ((unsigned int)f2bf(accO) << 16);
    }
}

// ---------- conv1d k=3 pad=1 + relu (128-thread blocks) ----------
template<int IPG, int OPG, int CINTOT>
__global__ void k_conv_t(int in_off, const float* __restrict__ w,
                         const float* __restrict__ bias, int out_off) {
    int id = blockIdx.x * 128 + threadIdx.x;
    if (id >= BB * H1 * TT) return;
    int t = id % TT, o = (id / TT) % H1, b = id / (TT * H1);
    const float* ip = g_buf + in_off + (b * CINTOT + (o / OPG) * IPG) * TT + t;
    const float* wp = w + o * IPG * 3;
    float a0 = bias[o], a1 = 0.f, a2 = 0.f;
    bool t0 = (t > 0), t1 = (t < TT - 1);
    #pragma unroll 4
    for (int ci = 0; ci < IPG; ++ci) {
        float v0 = t0 ? ip[ci * TT - 1] : 0.f;
        float v1 = ip[ci * TT];
        float v2 = t1 ? ip[ci * TT + 1] : 0.f;
        a0 = fmaf(v0, wp[ci * 3 + 0], a0);
        a1 = fmaf(v1, wp[ci * 3 + 1], a1);
        a2 = fmaf(v2, wp[ci * 3 + 2], a2);
    }
    g_buf[out_off + id] = fmaxf(a0 + a1 + a2, 0.f);
}

// ---------- merged s/e convs + pf conv ----------
__global__ void k_sepf(const float* __restrict__ ws1, const float* __restrict__ bs1,
                       const float* __restrict__ we1, const float* __restrict__ be1,
                       const float* __restrict__ wp, const float* __restrict__ bp) {
    int blk = blockIdx.x;
    if (blk < 400) {
        int sec = blk >= 200;
        int id = (blk - sec * 200) * 256 + threadIdx.x;
        if (id >= BB * H1 * TT) return;
        const float* w  = sec ? we1 : ws1;
        const float* bi = sec ? be1 : bs1;
        int out_off = sec ? OFF_EB : OFF_SB;
        int t = id % TT, o = (id / TT) % H1, b = id / (TT * H1);
        const float* ip = g_buf + OFF_H2 + (b * H1 + (o / 64) * 64) * TT + t;
        const float* wpp = w + o * 64 * 3;
        float a0 = bi[o], a1 = 0.f, a2 = 0.f;
        bool tl = (t > 0), th = (t < TT - 1);
        #pragma unroll 4
        for (int ci = 0; ci < 64; ++ci) {
            float v0 = tl ? ip[ci * TT - 1] : 0.f;
            float v1 = ip[ci * TT];
            float v2 = th ? ip[ci * TT + 1] : 0.f;
            a0 = fmaf(v0, wpp[ci * 3 + 0], a0);
            a1 = fmaf(v1, wpp[ci * 3 + 1], a1);
            a2 = fmaf(v2, wpp[ci * 3 + 2], a2);
        }
        g_buf[out_off + id] = fmaxf(a0 + a1 + a2, 0.f);
    } else {
        int id = (blk - 400) * 256 + threadIdx.x;
        if (id >= BB * H1 * TT) return;
        int t = id % TT, o = (id / TT) % H1, b = id / (TT * H1);
        const float* ip = g_buf + OFF_H2 + (b * H1) * TT + t;
        const float* wpp = wp + o * H1 * 3;
        float a0 = bp[o], a1 = 0.f, a2 = 0.f;
        bool tl = (t > 0), th = (t < TT - 1);
        #pragma unroll 4
        for (int ci = 0; ci < H1; ++ci) {
            float v0 = tl ? ip[ci * TT - 1] : 0.f;
            float v1 = ip[ci * TT];
            float v2 = th ? ip[ci * TT + 1] : 0.f;
            a0 = fmaf(v0, wpp[ci * 3 + 0], a0);
            a1 = fmaf(v1, wpp[ci * 3 + 1], a1);
            a2 = fmaf(v2, wpp[ci * 3 + 2], a2);
        }
        ((unsigned short*)(g_buf + OFF_PFT))[((size_t)b * 112 + t) * 256 + o] =
            f2bf(fmaxf(a0 + a1 + a2, 0.f));
    }
}

// ---------- merged: Am (MFMA A-build, quad-rotated layout) + q1f + heads ----------
#define Q1F_BLKS ((BB * NINVAL * 16 + 255) / 256)
__global__ __launch_bounds__(256) void k_amfh(
        const float* __restrict__ ws2, const float* __restrict__ bs2,
        const float* __restrict__ we2, const float* __restrict__ be2,
        float* __restrict__ out) {
    int blk = blockIdx.x;
    if (blk < 1792) {   // k_Am: ATb pairs, quad-rotated: ch c of row m at quad ((c>>2)+m)&7
        int mt = blk % 7, nt = (blk / 7) % 4, bn = blk / 28;
        int b = bn >> 5, n = bn & 31;
        int wv = threadIdx.x >> 6, lane = threadIdx.x & 63;
        int r = lane & 15, g = lane >> 4;
        const unsigned short* ap = (const unsigned short*)(g_buf + OFF_PFT)
                                   + ((size_t)b * 112 + mt * 16 + r) * 256 + g * 8;
        const unsigned short* bp = (const unsigned short*)(g_buf + OFF_W3B)
                                   + ((size_t)n * 512 + nt * 128 + wv * 32 + r) * 256 + g * 8;
        f32x4 acc0 = {0.f, 0.f, 0.f, 0.f}, acc1 = {0.f, 0.f, 0.f, 0.f};
        #pragma unroll
        for (int ks = 0; ks < 8; ++ks) {
            bf16x8 a  = *(const bf16x8*)(ap + ks * 32);
            bf16x8 b0 = *(const bf16x8*)(bp + ks * 32);
            bf16x8 b1 = *(const bf16x8*)(bp + 16 * 256 + ks * 32);
            acc0 = __builtin_amdgcn_mfma_f32_16x16x32_bf16(a, b0, acc0, 0, 0, 0);
            acc1 = __builtin_amdgcn_mfma_f32_16x16x32_bf16(a, b1, acc1, 0, 0, 0);
        }
        unsigned short* ATb = (unsigned short*)(g_buf + OFF_ATB);
        int og = nt * 4 + wv;
        size_t gb = (size_t)(b * 16 + og) * 3200;
        int c0 = r, c1 = 16 + r;
        int q0c = c0 >> 2, o0c = (c0 & 3) * 2;
        int q1c = c1 >> 2, o1c = (c1 & 3) * 2;
        #pragma unroll
        for (int reg = 0; reg < 4; ++reg) {
            int t = mt * 16 + g * 4 + reg;
            if (t < TT) {
                int m = n * 100 + t;
                unsigned short v0 = f2bf(acc0[reg] * (1.f / 3.f));
                unsigned short v1 = f2bf(acc1[reg] * (1.f / 3.f));
                size_t row = (gb + m) * 64;
                size_t base0 = row + (size_t)((((q0c + m) & 7) << 3) + o0c);
                size_t base1 = row + (size_t)((((q1c + m) & 7) << 3) + o1c);
                ATb[base0] = v0;
                ATb[base1] = v1;
                if (t > 0) {
                    size_t rowp = (gb + m - 1) * 64;
                    ATb[rowp + (size_t)((((q0c + m - 1) & 7) << 3) + o0c) + 1] = v0;
                    ATb[rowp + (size_t)((((q1c + m - 1) & 7) << 3) + o1c) + 1] = v1;
                }
                if (t == TT - 1) {
                    ATb[base0 + 1] = 0;
                    ATb[base1 + 1] = 0;
                }
            }
        }
        return;
    }
    if (blk < 1792 + Q1F_BLKS) {   // q1f: invalid (i>j) pixels only, rank-indexed
        int id = (blk - 1792) * 256 + threadIdx.x;
        if (id >= BB * NINVAL * 16) return;
        int c = id & 15;
        int rr = (id >> 4) % NINVAL;
        int b = id / (16 * NINVAL);
        int i = (int)((1.0 + sqrt(1.0 + 8.0 * (double)rr)) * 0.5);
        if (i < 1) i = 1; if (i > 99) i = 99;
        while ((i * (i - 1)) / 2 > rr) --i;
        while (((i + 1) * i) / 2 <= rr) ++i;
        int j = rr - (i * (i - 1)) / 2;        // j in [0, i) => i > j
        uint4 w = ((const uint4*)(g_buf + OFF_CINV))[c];
        unsigned short* P1 = (unsigned short*)(g_buf + OFF_P1) + (size_t)b * PSTRIDE;
        *(uint4*)(P1 + (size_t)((i + 1) * PADW + j + 1) * H2C + c * 8) = w;
        return;
    }
    {   // heads
        int which = blk - (1792 + Q1F_BLKS);
        const float* w  = which ? we2 : ws2;
        const float* bi = which ? be2 : bs2;
        int in_off = which ? OFF_EB : OFF_SB;
        int id = threadIdx.x;
        if (id >= BB * TT) return;
        int t = id % TT, b = id / TT;
        const float* ip = g_buf + in_off + b * H1 * TT + t;
        float acc = bi[0];
        for (int c = 0; c < H1; ++c) acc = fmaf(ip[c * TT], w[c], acc);
        out[40000 + which * 200 + id] = 1.f / (1.f + expf(-acc));
    }
}

// ---------- BM gather: 32 ch/block, k-split x2, bf16 partials, async LDS stage ----------
__global__ __launch_bounds__(256) void k_bm2() {
    __shared__ uint4 Ash[1600];                 // 200 rows x 8 quads (rotation baked in global)
    int qt = blockIdx.x, og = blockIdx.y, z = blockIdx.z;
    int b = z >> 1, half = z & 1;
    int tid = threadIdx.x;
    int lane = tid & 63, wv4 = tid >> 6;
    int v = qt * 256 + tid;
    bool val = (v < NVALID);
    int vv = val ? v : 0;
    const unsigned int* desc = (const unsigned int*)(g_buf + OFF_DESC);
    const uint4* src = (const uint4*)((const unsigned short*)(g_buf + OFF_ATB)
                                      + (size_t)(b * 16 + og) * 3200 * 64);
    float acc[32];
    #pragma unroll
    for (int c = 0; c < 32; ++c) acc[c] = 0.f;

    for (int st = half * 8; st < half * 8 + 8; ++st) {
        __syncthreads();
        for (int idx0 = wv4 * 64; idx0 < 1600; idx0 += 256)
            gload_lds16(src + st * 1600 + idx0 + lane, (void*)&Ash[idx0]);
        __syncthreads();
        #pragma unroll
        for (int kk = 0; kk < 6; ++kk) {
            unsigned int d = desc[(size_t)(st * 6 + kk) * 5056 + vv];
            int t2 = (int)(d & 0xFFFu) - st * 200;
            unsigned int mode = (d >> 12) & 3u;
            float dec = (float)(d >> 16) * (1.f / 65535.f);
            float w0 = (mode == 2u) ? 0.f : 1.f - dec;
            float w1 = (mode == 0u) ? dec : 0.f;
            unsigned int wpair;
            asm("v_cvt_pk_bf16_f32 %0, %1, %2" : "=v"(wpair) : "v"(w0), "v"(w1));
            int base = t2 << 3;
            uint4 A0 = Ash[base | ((0 + t2) & 7)];
            uint4 A1 = Ash[base | ((1 + t2) & 7)];
            uint4 A2 = Ash[base | ((2 + t2) & 7)];
            uint4 A3 = Ash[base | ((3 + t2) & 7)];
            uint4 A4 = Ash[base | ((4 + t2) & 7)];
            uint4 A5 = Ash[base | ((5 + t2) & 7)];
            uint4 A6 = Ash[base | ((6 + t2) & 7)];
            uint4 A7 = Ash[base | ((7 + t2) & 7)];
            dot2(acc[0],  A0.x, wpair); dot2(acc[1],  A0.y, wpair);
            dot2(acc[2],  A0.z, wpair); dot2(acc[3],  A0.w, wpair);
            dot2(acc[4],  A1.x, wpair); dot2(acc[5],  A1.y, wpair);
            dot2(acc[6],  A1.z, wpair); dot2(acc[7],  A1.w, wpair);
            dot2(acc[8],  A2.x, wpair); dot2(acc[9],  A2.y, wpair);
            dot2(acc[10], A2.z, wpair); dot2(acc[11], A2.w, wpair);
            dot2(acc[12], A3.x, wpair); dot2(acc[13], A3.y, wpair);
            dot2(acc[14], A3.z, wpair); dot2(acc[15], A3.w, wpair);
            dot2(acc[16], A4.x, wpair); dot2(acc[17], A4.y, wpair);
            dot2(acc[18], A4.z, wpair); dot2(acc[19], A4.w, wpair);
            dot2(acc[20], A5.x, wpair); dot2(acc[21], A5.y, wpair);
            dot2(acc[22], A5.z, wpair); dot2(acc[23], A5.w, wpair);
            dot2(acc[24], A6.x, wpair); dot2(acc[25], A6.y, wpair);
            dot2(acc[26], A6.z, wpair); dot2(acc[27], A6.w, wpair);
            dot2(acc[28], A7.x, wpair); dot2(acc[29], A7.y, wpair);
            dot2(acc[30], A7.z, wpair); dot2(acc[31], A7.w, wpair);
        }
    }
    if (val) {
        unsigned short* PB = (unsigned short*)(g_buf + OFF_PART)
                             + ((size_t)(b * 2 + half) * 5056 + v) * 512 + og * 32;
        unsigned int w[16];
        #pragma unroll
        for (int c2 = 0; c2 < 16; ++c2)
            w[c2] = (unsigned int)f2bf(acc[c2 * 2]) |
                    ((unsigned int)f2bf(acc[c2 * 2 + 1]) << 16);
        uint4* dst = (uint4*)PB;
        dst[0] = make_uint4(w[0],  w[1],  w[2],  w[3]);
        dst[1] = make_uint4(w[4],  w[5],  w[6],  w[7]);
        dst[2] = make_uint4(w[8],  w[9],  w[10], w[11]);
        dst[3] = make_uint4(w[12], w[13], w[14], w[15]);
    }
}

#define MFMA16(a, b, c) __builtin_amdgcn_mfma_f32_16x16x32_bf16(a, b, c, 0, 0, 0)

// ---------- q1: valid pixels only; fuses bf16-partial combine + bias + relu ----------
__global__ __launch_bounds__(256) void k_q1m(const float* __restrict__ bias,
                                             const float* __restrict__ b3d) {
    __shared__ uint4 As[2048];
    __shared__ int qmap[32];
    const unsigned short* Bw = (const unsigned short*)(g_buf + OFF_WQ1B);
    unsigned short* P1 = (unsigned short*)(g_buf + OFF_P1);
    int m0 = blockIdx.x * 32, b = blockIdx.y;
    int tid = threadIdx.x;
    if (tid < 32) {
        int v = m0 + tid; if (v >= NVALID) v = NVALID - 1;
        int i = (int)(100.5 - sqrt(10100.25 - 2.0 * (double)v));
        if (i < 0) i = 0; if (i > 99) i = 99;
        while (100 * (i + 1) - ((i + 1) * i) / 2 <= v && i < 99) ++i;
        while (100 * i - (i * (i - 1)) / 2 > v && i > 0) --i;
        int j = i + (v - (100 * i - (i * (i - 1)) / 2));
        qmap[tid] = i * 100 + j;
    }
    __syncthreads();
    const unsigned short* PB = (const unsigned short*)(g_buf + OFF_PART);
    const size_t PSET = (size_t)5056 * 512;    // ush per partial set
    for (int idx = tid; idx < 2048; idx += 256) {
        int px = idx >> 6, ch = idx & 63;      // ch = octet of channels
        int vr = m0 + px; if (vr >= NVALID) vr = NVALID - 1;
        size_t base = ((size_t)(b * 2) * 5056 + vr) * 512 + ch * 8;
        uint4 s4 = *(const uint4*)(PB + base);
        uint4 t4 = *(const uint4*)(PB + base + PSET);
        const float* bb = b3d + ch * 8;
        unsigned int su[4] = {s4.x, s4.y, s4.z, s4.w};
        unsigned int tu[4] = {t4.x, t4.y, t4.z, t4.w};
        unsigned int w[4];
        #pragma unroll
        for (int wd = 0; wd < 4; ++wd) {
            float x0 = fmaxf(bf2f((unsigned short)su[wd]) +
                             bf2f((unsigned short)tu[wd]) + bb[wd * 2], 0.f);
            float x1 = fmaxf(bf2f((unsigned short)(su[wd] >> 16)) +
                             bf2f((unsigned short)(tu[wd] >> 16)) + bb[wd * 2 + 1], 0.f);
            w[wd] = (unsigned int)f2bf(x0) | ((unsigned int)f2bf(x1) << 16);
        }
        int ch2 = ch ^ (px & 7) ^ (((px >> 3) & 1) << 3);
        As[px * 64 + ch2] = make_uint4(w[0], w[1], w[2], w[3]);
    }
    __syncthreads();
    int wv = tid >> 6, lane = tid & 63, r = lane & 15, g = lane >> 4;
    int q0 = wv * 32;
    f32x4 acc[2][2] = {{{0.f,0.f,0.f,0.f},{0.f,0.f,0.f,0.f}},{{0.f,0.f,0.f,0.f},{0.f,0.f,0.f,0.f}}};
    bf16x8 Bb[4][2], Aa[2][2];
#define Q1_LB(slot, it_) { const unsigned short* bp = Bw + (size_t)(q0 + r) * 512 + (it_) * 32 + g * 8; \
    Bb[slot][0] = *(const bf16x8*)bp; Bb[slot][1] = *(const bf16x8*)(bp + 16 * 512); }
#define Q1_LA(slot, it_) { int ch = (it_) * 4 + g; \
    int px0 = r, px1 = 16 + r; \
    Aa[slot][0] = *(const bf16x8*)&As[px0 * 64 + (ch ^ (px0 & 7) ^ (((px0 >> 3) & 1) << 3))]; \
    Aa[slot][1] = *(const bf16x8*)&As[px1 * 64 + (ch ^ (px1 & 7) ^ (((px1 >> 3) & 1) << 3))]; }
    Q1_LB(0, 0); Q1_LB(1, 1); Q1_LB(2, 2); Q1_LA(0, 0);
    #pragma unroll
    for (int it = 0; it < 16; ++it) {
        if (it + 3 < 16) Q1_LB((it + 3) & 3, it + 3);
        if (it + 1 < 16) Q1_LA((it + 1) & 1, it + 1);
        int s = it & 3, sa = it & 1;
        acc[0][0] = MFMA16(Aa[sa][0], Bb[s][0], acc[0][0]);
        acc[0][1] = MFMA16(Aa[sa][0], Bb[s][1], acc[0][1]);
        acc[1][0] = MFMA16(Aa[sa][1], Bb[s][0], acc[1][0]);
        acc[1][1] = MFMA16(Aa[sa][1], Bb[s][1], acc[1][1]);
    }
    float bi0 = bias[q0 + r], bi1 = bias[q0 + 16 + r];
    unsigned short* Pout = P1 + (size_t)b * PSTRIDE;
    #pragma unroll
    for (int mt = 0; mt < 2; ++mt)
        #pragma unroll
        for (int reg = 0; reg < 4; ++reg) {
            int px = mt * 16 + g * 4 + reg;
            if (m0 + px < NVALID) {
                int q = qmap[px];
                int i = q / 100, j = q - i * 100;
                size_t base = (size_t)((i + 1) * PADW + j + 1) * H2C;
                Pout[base + q0 + r]      = f2bf(fmaxf(acc[mt][0][reg] + bi0, 0.f));
                Pout[base + q0 + 16 + r] = f2bf(fmaxf(acc[mt][1][reg] + bi1, 0.f));
            }
        }
}

// ---------- 3x3 conv 128->128, M=64 (2 output rows/block); FQ4: fused q4+sigmoid ----------
template<int FQ4>
__global__ __launch_bounds__(256) void k_c3m2(int in_off, int w_off,
                                              const float* __restrict__ bias,
                                              int out_off,
                                              const float* __restrict__ wq4,
                                              const float* __restrict__ bq4,
                                              float* __restrict__ out) {
    __shared__ uint4 As[2176];                 // 4 rows x 34 px x 16 oct
    const unsigned short* Pin = (const unsigned short*)(g_buf + in_off);
    const unsigned short* wB  = (const unsigned short*)(g_buf + w_off);
    int jt = blockIdx.x, y = blockIdx.y, b = blockIdx.z;
    int i0 = y * 2;
    int j0 = (jt == 3) ? 68 : jt * 32;
    int tid = threadIdx.x;
    const unsigned short* Ab = Pin + (size_t)b * PSTRIDE;
    for (int idx = tid; idx < 2176; idx += 256) {
        int row = idx / 544, rem = idx - row * 544;
        int px = rem >> 4, ch = rem & 15;
        int ch2 = ch ^ (px & 7) ^ (((px >> 3) & 1) << 3);
        As[(row * 34 + px) * 16 + ch2] =
            *(const uint4*)(Ab + (size_t)((i0 + row) * PADW + j0 + px) * H2C + ch * 8);
    }
    __syncthreads();
    int wv = tid >> 6, lane = tid & 63, r = lane & 15, g = lane >> 4;
    int q0 = wv * 32;
    f32x4 acc[2][2][2];
    #pragma unroll
    for (int a = 0; a < 2; ++a)
        #pragma unroll
        for (int m = 0; m < 2; ++m)
            #pragma unroll
            for (int h = 0; h < 2; ++h) acc[a][m][h] = (f32x4){0.f, 0.f, 0.f, 0.f};
    bf16x8 Bb[4][2], Aa[2][4];
#define C2_LB(slot, it_) { int tap = (it_) >> 2, cc = (it_) & 3; \
    const unsigned short* bp = wB + (size_t)(q0 + r) * 1152 + tap * 128 + cc * 32 + g * 8; \
    Bb[slot][0] = *(const bf16x8*)bp; Bb[slot][1] = *(const bf16x8*)(bp + 16 * 1152); }
#define C2_LA(slot, it_) { int tap = (it_) >> 2, cc = (it_) & 3; \
    int ky = tap / 3, kx = tap - ky * 3; int ch = cc * 4 + g; \
    int px0 = r + kx, px1 = 16 + r + kx; \
    Aa[slot][0] = *(const bf16x8*)&As[(ky * 34 + px0) * 16 + (ch ^ (px0 & 7) ^ (((px0 >> 3) & 1) << 3))]; \
    Aa[slot][1] = *(const bf16x8*)&As[(ky * 34 + px1) * 16 + (ch ^ (px1 & 7) ^ (((px1 >> 3) & 1) << 3))]; \
    Aa[slot][2] = *(const bf16x8*)&As[((ky + 1) * 34 + px0) * 16 + (ch ^ (px0 & 7) ^ (((px0 >> 3) & 1) << 3))]; \
    Aa[slot][3] = *(const bf16x8*)&As[((ky + 1) * 34 + px1) * 16 + (ch ^ (px1 & 7) ^ (((px1 >> 3) & 1) << 3))]; }
    C2_LB(0, 0); C2_LB(1, 1); C2_LB(2, 2); C2_LA(0, 0);
    #pragma unroll
    for (int it = 0; it < 36; ++it) {
        if (it + 3 < 36) C2_LB((it + 3) & 3, it + 3);
        if (it + 1 < 36) C2_LA((it + 1) & 1, it + 1);
        int s = it & 3, sa = it & 1;
        acc[0][0][0] = MFMA16(Aa[sa][0], Bb[s][0], acc[0][0][0]);
        acc[0][0][1] = MFMA16(Aa[sa][0], Bb[s][1], acc[0][0][1]);
        acc[0][1][0] = MFMA16(Aa[sa][1], Bb[s][0], acc[0][1][0]);
        acc[0][1][1] = MFMA16(Aa[sa][1], Bb[s][1], acc[0][1][1]);
        acc[1][0][0] = MFMA16(Aa[sa][2], Bb[s][0], acc[1][0][0]);
        acc[1][0][1] = MFMA16(Aa[sa][2], Bb[s][1], acc[1][0][1]);
        acc[1][1][0] = MFMA16(Aa[sa][3], Bb[s][0], acc[1][1][0]);
        acc[1][1][1] = MFMA16(Aa[sa][3], Bb[s][1], acc[1][1][1]);
    }
    float bi0 = bias[q0 + r], bi1 = bias[q0 + 16 + r];
    if constexpr (!FQ4) {
        unsigned short* Ob = (unsigned short*)(g_buf + out_off) + (size_t)b * PSTRIDE;
        #pragma unroll
        for (int orow = 0; orow < 2; ++orow)
            #pragma unroll
            for (int mt = 0; mt < 2; ++mt)
                #pragma unroll
                for (int reg = 0; reg < 4; ++reg) {
                    int j = j0 + mt * 16 + g * 4 + reg;
                    size_t base = (size_t)((i0 + orow + 1) * PADW + j + 1) * H2C;
                    Ob[base + q0 + r]      = f2bf(fmaxf(acc[orow][mt][0][reg] + bi0, 0.f));
                    Ob[base + q0 + 16 + r] = f2bf(fmaxf(acc[orow][mt][1][reg] + bi1, 0.f));
                }
    } else {
        __shared__ float part[4][2][2][32];
        float w40a = wq4[q0 + r],       w40b = wq4[q0 + 16 + r];
        float w41a = wq4[128 + q0 + r], w41b = wq4[128 + q0 + 16 + r];
        #pragma unroll
        for (int orow = 0; orow < 2; ++orow)
            #pragma unroll
            for (int mt = 0; mt < 2; ++mt)
                #pragma unroll
                for (int reg = 0; reg < 4; ++reg) {
                    float x0 = fmaxf(acc[orow][mt][0][reg] + bi0, 0.f);
                    float x1 = fmaxf(acc[orow][mt][1][reg] + bi1, 0.f);
                    float p0 = x0 * w40a + x1 * w40b;
                    float p1 = x0 * w41a + x1 * w41b;
                    #pragma unroll
                    for (int off = 1; off < 16; off <<= 1) {
                        p0 += __shfl_xor(p0, off);
                        p1 += __shfl_xor(p1, off);
                    }
                    if (r == 0) {
                        int px = mt * 16 + g * 4 + reg;
                        part[wv][orow][0][px] = p0;
                        part[wv][orow][1][px] = p1;
                    }
                }
        __syncthreads();
        if (tid < 128) {
            int px = tid & 31, hd = (tid >> 5) & 1, orow = tid >> 6;
            float s = part[0][orow][hd][px] + part[1][orow][hd][px] +
                      part[2][orow][hd][px] + part[3][orow][hd][px] + bq4[hd];
            out[(size_t)(b * 2 + hd) * IJ + (i0 + orow) * 100 + (j0 + px)] =
                1.f / (1.f + expf(-s));
        }
    }
}

extern "C" void kernel_launch(void* const* d_in, const int* in_sizes, int n_in,
                              void* d_out, int out_size, void* d_ws, size_t ws_size,
                              hipStream_t stream) {
    const float* x   = (const float*)d_in[0];
    const float* wb1 = (const float*)d_in[1];  const float* bb1 = (const float*)d_in[2];
    const float* wb2 = (const float*)d_in[3];  const float* bb2 = (const float*)d_in[4];
    const float* ws1 = (const float*)d_in[5];  const float* bs1 = (const float*)d_in[6];
    const float* ws2 = (const float*)d_in[7];  const float* bs2 = (const float*)d_in[8];
    const float* we1 = (const float*)d_in[9];  const float* be1 = (const float*)d_in[10];
    const float* we2 = (const float*)d_in[11]; const float* be2 = (const float*)d_in[12];
    const float* wp  = (const float*)d_in[13]; const float* bp  = (const float*)d_in[14];
    const float* w3d = (const float*)d_in[15]; const float* b3d = (const float*)d_in[16];
    const float* wq1 = (const float*)d_in[17]; const float* bq1 = (const float*)d_in[18];
    const float* wq2 = (const float*)d_in[19]; const float* bq2 = (const float*)d_in[20];
    const float* wq3 = (const float*)d_in[21]; const float* bq3 = (const float*)d_in[22];
    const float* wq4 = (const float*)d_in[23]; const float* bq4 = (const float*)d_in[24];
    float* out = (float*)d_out;

    k_prepw<<<512 + (PREP_IDS + 255) / 256, 256, 0, stream>>>(wq1, wq2, wq3, x, b3d, bq1, w3d);
    k_conv_t<100, 64, 400><<<400, 128, 0, stream>>>(OFF_XT, wb1, bb1, OFF_H1);
    k_conv_t<64, 64, 256><<<400, 128, 0, stream>>>(OFF_H1, wb2, bb2, OFF_H2);
    k_sepf<<<600, 256, 0, stream>>>(ws1, bs1, we1, be1, wp, bp);
    k_amfh<<<1792 + Q1F_BLKS + 2, 256, 0, stream>>>(ws2, bs2, we2, be2, out);
    k_bm2<<<dim3(20, 16, 4), 256, 0, stream>>>();
    k_q1m<<<dim3((NVALID + 31) / 32, 2), 256, 0, stream>>>(bq1, b3d);
    k_c3m2<0><<<dim3(4, 50, 2), 256, 0, stream>>>(OFF_P1, OFF_WQ2B, bq2, OFF_P2,
                                                  nullptr, nullptr, nullptr);
    k_c3m2<1><<<dim3(4, 50, 2), 256, 0, stream>>>(OFF_P2, OFF_WQ3B, bq3, 0,
                                                  wq4, bq4, out);
}

// Round 24
// 202.607 us; speedup vs baseline: 1.2482x; 1.0873x over previous
//
#include <hip/hip_runtime.h>
#include <hip/hip_bf16.h>
#include <math.h>

#define TT  100
#define CIN 400
#define H1  256
#define NS  32
#define NP  96
#define H3  512
#define H2C 128
#define BB  2
#define IJ  10000
#define NVALID 5050
#define NINVAL 4950
#define PADW 102
#define PPIX 10432
#define PSTRIDE (PPIX * H2C)

typedef __attribute__((ext_vector_type(8))) short bf16x8;
typedef __attribute__((ext_vector_type(4))) float f32x4;

// ---- static scratch (float units) ----
#define OFF_XT   0
#define OFF_H1   80000
#define OFF_H2   131200
#define OFF_SB   182400
#define OFF_EB   233600
#define OFF_PF   284800
#define OFF_ATB  336000      // bf16 pairs ATb[b][16 og32][3200 m][8 quad-rotated][4ch][2]
#define OFF_P1   8732800
#define OFF_P2   10068096
#define OFF_CINV 11403392    // uint[64]: c_inv as bf16 pairs
#define OFF_WQ1B 12683392
#define OFF_WQ2B 12716160
#define OFF_WQ3B 12789888
#define OFF_DESC 12863616    // u32 [96][5056] valid-rank indexed
#define OFF_PFT  13846656    // bf16 [b][112][256]
#define OFF_W3B  13875328    // bf16 [n][o][c]
#define OFF_PART 15972480    // bf16 [(b*2+half)][5056 v][512 ch]
#define G_TOTAL  21149824

__device__ __align__(16) float g_buf[G_TOTAL];

__device__ inline unsigned short f2bf(float f) {
    __hip_bfloat16 h = __float2bfloat16(f);
    return *(unsigned short*)&h;
}
__device__ inline float bf2f(unsigned short u) {
    union { unsigned int i; float f; } v; v.i = ((unsigned int)u) << 16; return v.f;
}
__device__ inline void dot2(float& acc, unsigned int a, unsigned int w) {
    asm("v_dot2_f32_bf16 %0, %1, %2, %0" : "+v"(acc) : "v"(a), "v"(w));
}
// async global->LDS, 16B per lane; lds dest = wave-uniform base + lane*16
__device__ inline void gload_lds16(const void* g, void* l) {
    __builtin_amdgcn_global_load_lds(
        (const __attribute__((address_space(1))) unsigned int*)g,
        (__attribute__((address_space(3))) unsigned int*)l, 16, 0, 0);
}

// ---------- merged prep: w3prep blocks [0,512) + element-wise prep ----------
#define PREP_IDS (65536 + 147456 + 147456 + 51712 + 5056 + BB * TT * CIN + BB * 12 * 256 + 128)
__global__ __launch_bounds__(256) void k_prepw(
        const float* __restrict__ wq1, const float* __restrict__ wq2,
        const float* __restrict__ wq3, const float* __restrict__ x,
        const float* __restrict__ b3d, const float* __restrict__ bq1,
        const float* __restrict__ w3d) {
    __shared__ float tile[8192];
    int tid = threadIdx.x;
    if (blockIdx.x < 512) {   // w3b[n][o][c] bf16 from w3d[o][c][n]
        int o = blockIdx.x;
        const float* src = w3d + o * 8192;
        for (int idx = tid; idx < 8192; idx += 256) tile[idx] = src[idx];
        __syncthreads();
        int n = tid & 31, ch = tid >> 5;
        unsigned short* w3b = (unsigned short*)(g_buf + OFF_W3B);
        unsigned int w[16];
        #pragma unroll
        for (int c2 = 0; c2 < 16; ++c2) {
            int c = ch * 32 + c2 * 2;
            w[c2] = (unsigned int)f2bf(tile[c * 32 + n]) |
                    ((unsigned int)f2bf(tile[(c + 1) * 32 + n]) << 16);
        }
        uint4* dst = (uint4*)(w3b + ((size_t)n * 512 + o) * 256 + ch * 32);
        dst[0] = make_uint4(w[0], w[1], w[2], w[3]);
        dst[1] = make_uint4(w[4], w[5], w[6], w[7]);
        dst[2] = make_uint4(w[8], w[9], w[10], w[11]);
        dst[3] = make_uint4(w[12], w[13], w[14], w[15]);
        return;
    }
    int id = (blockIdx.x - 512) * 256 + tid;
    if (id < 65536) {
        ((unsigned short*)(g_buf + OFF_WQ1B))[id] = f2bf(wq1[id]);
        return;
    }
    id -= 65536;
    if (id < 147456) {
        int q = id / 1152, k = id % 1152, tap = k >> 7, c = k & 127;
        ((unsigned short*)(g_buf + OFF_WQ2B))[id] = f2bf(wq2[(q * 128 + c) * 9 + tap]);
        return;
    }
    id -= 147456;
    if (id < 147456) {
        int q = id / 1152, k = id % 1152, tap = k >> 7, c = k & 127;
        ((unsigned short*)(g_buf + OFF_WQ3B))[id] = f2bf(wq3[(q * 128 + c) * 9 + tap]);
        return;
    }
    id -= 147456;
    if (id < 51712) {   // halo zero
        int c = id & 31;
        int h = (id >> 5) % 404;
        int bb = ((id >> 5) / 404) & 1;
        int buf = id / 25856;
        int pix;
        if (h < 102) pix = h;
        else if (h < 204) pix = 101 * PADW + (h - 102);
        else { int q = h - 204; pix = (1 + (q >> 1)) * PADW + ((q & 1) ? 101 : 0); }
        unsigned short* P = (unsigned short*)(g_buf + (buf ? OFF_P2 : OFF_P1))
                            + (size_t)bb * PSTRIDE + (size_t)pix * H2C;
        ((uint2*)P)[c] = make_uint2(0u, 0u);
        return;
    }
    id -= 51712;
    if (id < 5056) {   // desc: one thread per rank v, loop over all k
        int v = id;
        bool valid = (v < NVALID);
        double xmn = 0.0, plen = 0.0;
        if (valid) {
            int i = (int)(100.5 - sqrt(10100.25 - 2.0 * (double)v));
            if (i < 0) i = 0; if (i > 99) i = 99;
            while (100 * (i + 1) - ((i + 1) * i) / 2 <= v && i < 99) ++i;
            while (100 * i - (i * (i - 1)) / 2 > v && i > 0) --i;
            int j = i + (v - (100 * i - (i * (i - 1)) / 2));
            double len = (double)(j - i + 2);
            xmn = (double)i - 0.5 * len;
            double xmx = (double)(j + 1) + 0.5 * len;
            plen = (xmx - xmn) / 95.0;
        }
        unsigned int* dout = (unsigned int*)(g_buf + OFF_DESC);
        for (int k = 0; k < NP; ++k) {
            unsigned int nb = (unsigned int)((k / 3) * 100);
            unsigned int d = nb | (2u << 12);
            if (valid) {
                double s = __dadd_rn(xmn, __dmul_rn(plen, (double)k));
                double tr = trunc(s);
                double dec = s - tr;
                int dn = (int)tr;
                int up = (int)ceil(s);
                bool okd = (unsigned)dn < (unsigned)TT;
                bool oku = (unsigned)up < (unsigned)TT;
                if (!okd) d = nb | (2u << 12);
                else if (oku && up == dn + 1) {
                    unsigned int dfx = (unsigned int)__double2int_rn(dec * 65535.0);
                    d = (nb + dn) | (dfx << 16);
                } else if (oku) {
                    d = (nb + dn) | (1u << 12);
                } else {
                    unsigned int dfx = (unsigned int)__double2int_rn(dec * 65535.0);
                    d = (nb + dn) | (1u << 12) | (dfx << 16);
                }
            }
            dout[(size_t)k * 5056 + v] = d;
        }
        return;
    }
    id -= 5056;
    if (id < BB * TT * CIN) {   // x transpose
        int c = id % CIN, t = (id / CIN) % TT, b = id / (CIN * TT);
        g_buf[OFF_XT + (b * CIN + c) * TT + t] = x[id];
        return;
    }
    id -= BB * TT * CIN;
    if (id < BB * 12 * 256) {   // zero pfT pad rows
        int c = id & 255, tp = (id >> 8) % 12, b = id / (12 * 256);
        ((unsigned short*)(g_buf + OFF_PFT))[((size_t)b * 112 + 100 + tp) * 256 + c] = 0;
        return;
    }
    id -= BB * 12 * 256;
    if (id < 128) {   // c_inv[q] = relu(wq1 . relu(b3d) + bq1)
        int q = id;
        float acc = bq1[q];
        const float* wr = wq1 + q * 512;
        #pragma unroll 8
        for (int c = 0; c < 512; ++c) acc = fmaf(wr[c], fmaxf(b3d[c], 0.f), acc);
        acc = fmaxf(acc, 0.f);
        float accO = __shfl_xor(acc, 1);
        if ((id & 1) == 0)
            ((unsigned int*)(g_buf + OFF_CINV))[id >> 1] =
                (unsigned int)f2bf(acc) | ((unsigned int)f2bf(accO) << 16);
    }
}

// ---------- conv1d k=3 pad=1 + relu; wave-split over ci halves (coalescing kept) ----------
template<int IPG, int OPG, int CINTOT>
__global__ __launch_bounds__(256) void k_conv_t(int in_off, const float* __restrict__ w,
                                                const float* __restrict__ bias, int out_off) {
    __shared__ float part[128];
    int tid = threadIdx.x;
    int half = tid >> 7, lid = tid & 127;
    int outp = blockIdx.x * 128 + lid;            // grid exact: total/128 blocks
    int t = outp % TT, o = (outp / TT) % H1, b = outp / (TT * H1);
    const float* ip = g_buf + in_off
                    + (b * CINTOT + (o / OPG) * IPG + half * (IPG / 2)) * TT + t;
    const float* wp = w + o * IPG * 3 + half * (IPG / 2) * 3;
    float a0 = 0.f, a1 = 0.f, a2 = 0.f;
    bool t0 = (t > 0), t1 = (t < TT - 1);
    #pragma unroll 4
    for (int ci = 0; ci < IPG / 2; ++ci) {
        float v0 = t0 ? ip[ci * TT - 1] : 0.f;
        float v1 = ip[ci * TT];
        float v2 = t1 ? ip[ci * TT + 1] : 0.f;
        a0 = fmaf(v0, wp[ci * 3 + 0], a0);
        a1 = fmaf(v1, wp[ci * 3 + 1], a1);
        a2 = fmaf(v2, wp[ci * 3 + 2], a2);
    }
    float a = a0 + a1 + a2;
    if (half) part[lid] = a;
    __syncthreads();
    if (!half) g_buf[out_off + outp] = fmaxf(a + part[lid] + bias[o], 0.f);
}

// ---------- merged s/e convs + pf conv; wave-split over ci halves ----------
__global__ __launch_bounds__(256) void k_sepf(
        const float* __restrict__ ws1, const float* __restrict__ bs1,
        const float* __restrict__ we1, const float* __restrict__ be1,
        const float* __restrict__ wp, const float* __restrict__ bp) {
    __shared__ float part[128];
    int blk = blockIdx.x;
    int tid = threadIdx.x;
    int half = tid >> 7, lid = tid & 127;
    if (blk < 800) {    // s (0-399) / e (400-799), grouped 64-ch: 32 ci per half
        int sec = blk >= 400;
        int outp = (blk - sec * 400) * 128 + lid;
        const float* w  = sec ? we1 : ws1;
        const float* bi = sec ? be1 : bs1;
        int out_off = sec ? OFF_EB : OFF_SB;
        int t = outp % TT, o = (outp / TT) % H1, b = outp / (TT * H1);
        const float* ip = g_buf + OFF_H2 + (b * H1 + (o / 64) * 64 + half * 32) * TT + t;
        const float* wpp = w + o * 64 * 3 + half * 32 * 3;
        float a0 = 0.f, a1 = 0.f, a2 = 0.f;
        bool tl = (t > 0), th = (t < TT - 1);
        #pragma unroll 4
        for (int ci = 0; ci < 32; ++ci) {
            float v0 = tl ? ip[ci * TT - 1] : 0.f;
            float v1 = ip[ci * TT];
            float v2 = th ? ip[ci * TT + 1] : 0.f;
            a0 = fmaf(v0, wpp[ci * 3 + 0], a0);
            a1 = fmaf(v1, wpp[ci * 3 + 1], a1);
            a2 = fmaf(v2, wpp[ci * 3 + 2], a2);
        }
        float a = a0 + a1 + a2;
        if (half) part[lid] = a;
        __syncthreads();
        if (!half) g_buf[out_off + outp] = fmaxf(a + part[lid] + bi[o], 0.f);
    } else {            // pf conv (256 ch): 128 ci per half
        int outp = (blk - 800) * 128 + lid;
        int t = outp % TT, o = (outp / TT) % H1, b = outp / (TT * H1);
        const float* ip = g_buf + OFF_H2 + (b * H1 + half * 128) * TT + t;
        const float* wpp = wp + o * H1 * 3 + half * 128 * 3;
        float a0 = 0.f, a1 = 0.f, a2 = 0.f;
        bool tl = (t > 0), th = (t < TT - 1);
        #pragma unroll 4
        for (int ci = 0; ci < 128; ++ci) {
            float v0 = tl ? ip[ci * TT - 1] : 0.f;
            float v1 = ip[ci * TT];
            float v2 = th ? ip[ci * TT + 1] : 0.f;
            a0 = fmaf(v0, wpp[ci * 3 + 0], a0);
            a1 = fmaf(v1, wpp[ci * 3 + 1], a1);
            a2 = fmaf(v2, wpp[ci * 3 + 2], a2);
        }
        float a = a0 + a1 + a2;
        if (half) part[lid] = a;
        __syncthreads();
        if (!half)
            ((unsigned short*)(g_buf + OFF_PFT))[((size_t)b * 112 + t) * 256 + o] =
                f2bf(fmaxf(a + part[lid] + bp[o], 0.f));
    }
}

// ---------- merged: Am (MFMA A-build, quad-rotated layout) + q1f + heads ----------
#define Q1F_BLKS ((BB * NINVAL * 16 + 255) / 256)
__global__ __launch_bounds__(256) void k_amfh(
        const float* __restrict__ ws2, const float* __restrict__ bs2,
        const float* __restrict__ we2, const float* __restrict__ be2,
        float* __restrict__ out) {
    int blk = blockIdx.x;
    if (blk < 1792) {   // k_Am: ATb pairs, quad-rotated: ch c of row m at quad ((c>>2)+m)&7
        int mt = blk % 7, nt = (blk / 7) % 4, bn = blk / 28;
        int b = bn >> 5, n = bn & 31;
        int wv = threadIdx.x >> 6, lane = threadIdx.x & 63;
        int r = lane & 15, g = lane >> 4;
        const unsigned short* ap = (const unsigned short*)(g_buf + OFF_PFT)
                                   + ((size_t)b * 112 + mt * 16 + r) * 256 + g * 8;
        const unsigned short* bp = (const unsigned short*)(g_buf + OFF_W3B)
                                   + ((size_t)n * 512 + nt * 128 + wv * 32 + r) * 256 + g * 8;
        f32x4 acc0 = {0.f, 0.f, 0.f, 0.f}, acc1 = {0.f, 0.f, 0.f, 0.f};
        #pragma unroll
        for (int ks = 0; ks < 8; ++ks) {
            bf16x8 a  = *(const bf16x8*)(ap + ks * 32);
            bf16x8 b0 = *(const bf16x8*)(bp + ks * 32);
            bf16x8 b1 = *(const bf16x8*)(bp + 16 * 256 + ks * 32);
            acc0 = __builtin_amdgcn_mfma_f32_16x16x32_bf16(a, b0, acc0, 0, 0, 0);
            acc1 = __builtin_amdgcn_mfma_f32_16x16x32_bf16(a, b1, acc1, 0, 0, 0);
        }
        unsigned short* ATb = (unsigned short*)(g_buf + OFF_ATB);
        int og = nt * 4 + wv;
        size_t gb = (size_t)(b * 16 + og) * 3200;
        int c0 = r, c1 = 16 + r;
        int q0c = c0 >> 2, o0c = (c0 & 3) * 2;
        int q1c = c1 >> 2, o1c = (c1 & 3) * 2;
        #pragma unroll
        for (int reg = 0; reg < 4; ++reg) {
            int t = mt * 16 + g * 4 + reg;
            if (t < TT) {
                int m = n * 100 + t;
                unsigned short v0 = f2bf(acc0[reg] * (1.f / 3.f));
                unsigned short v1 = f2bf(acc1[reg] * (1.f / 3.f));
                size_t row = (gb + m) * 64;
                size_t base0 = row + (size_t)((((q0c + m) & 7) << 3) + o0c);
                size_t base1 = row + (size_t)((((q1c + m) & 7) << 3) + o1c);
                ATb[base0] = v0;
                ATb[base1] = v1;
                if (t > 0) {
                    size_t rowp = (gb + m - 1) * 64;
                    ATb[rowp + (size_t)((((q0c + m - 1) & 7) << 3) + o0c) + 1] = v0;
                    ATb[rowp + (size_t)((((q1c + m - 1) & 7) << 3) + o1c) + 1] = v1;
                }
                if (t == TT - 1) {
                    ATb[base0 + 1] = 0;
                    ATb[base1 + 1] = 0;
                }
            }
        }
        return;
    }
    if (blk < 1792 + Q1F_BLKS) {   // q1f: invalid (i>j) pixels only, rank-indexed
        int id = (blk - 1792) * 256 + threadIdx.x;
        if (id >= BB * NINVAL * 16) return;
        int c = id & 15;
        int rr = (id >> 4) % NINVAL;
        int b = id / (16 * NINVAL);
        int i = (int)((1.0 + sqrt(1.0 + 8.0 * (double)rr)) * 0.5);
        if (i < 1) i = 1; if (i > 99) i = 99;
        while ((i * (i - 1)) / 2 > rr) --i;
        while (((i + 1) * i) / 2 <= rr) ++i;
        int j = rr - (i * (i - 1)) / 2;        // j in [0, i) => i > j
        uint4 w = ((const uint4*)(g_buf + OFF_CINV))[c];
        unsigned short* P1 = (unsigned short*)(g_buf + OFF_P1) + (size_t)b * PSTRIDE;
        *(uint4*)(P1 + (size_t)((i + 1) * PADW + j + 1) * H2C + c * 8) = w;
        return;
    }
    {   // heads
        int which = blk - (1792 + Q1F_BLKS);
        const float* w  = which ? we2 : ws2;
        const float* bi = which ? be2 : bs2;
        int in_off = which ? OFF_EB : OFF_SB;
        int id = threadIdx.x;
        if (id >= BB * TT) return;
        int t = id % TT, b = id / TT;
        const float* ip = g_buf + in_off + b * H1 * TT + t;
        float acc = bi[0];
        for (int c = 0; c < H1; ++c) acc = fmaf(ip[c * TT], w[c], acc);
        out[40000 + which * 200 + id] = 1.f / (1.f + expf(-acc));
    }
}

// ---------- BM gather: 32 ch/block, k-split x2, bf16 partials, async LDS stage ----------
__global__ __launch_bounds__(256) void k_bm2() {
    __shared__ uint4 Ash[1600];                 // 200 rows x 8 quads (rotation baked in global)
    int qt = blockIdx.x, og = blockIdx.y, z = blockIdx.z;
    int b = z >> 1, half = z & 1;
    int tid = threadIdx.x;
    int lane = tid & 63, wv4 = tid >> 6;
    int v = qt * 256 + tid;
    bool val = (v < NVALID);
    int vv = val ? v : 0;
    const unsigned int* desc = (const unsigned int*)(g_buf + OFF_DESC);
    const uint4* src = (const uint4*)((const unsigned short*)(g_buf + OFF_ATB)
                                      + (size_t)(b * 16 + og) * 3200 * 64);
    float acc[32];
    #pragma unroll
    for (int c = 0; c < 32; ++c) acc[c] = 0.f;

    for (int st = half * 8; st < half * 8 + 8; ++st) {
        __syncthreads();
        for (int idx0 = wv4 * 64; idx0 < 1600; idx0 += 256)
            gload_lds16(src + st * 1600 + idx0 + lane, (void*)&Ash[idx0]);
        __syncthreads();
        #pragma unroll
        for (int kk = 0; kk < 6; ++kk) {
            unsigned int d = desc[(size_t)(st * 6 + kk) * 5056 + vv];
            int t2 = (int)(d & 0xFFFu) - st * 200;
            unsigned int mode = (d >> 12) & 3u;
            float dec = (float)(d >> 16) * (1.f / 65535.f);
            float w0 = (mode == 2u) ? 0.f : 1.f - dec;
            float w1 = (mode == 0u) ? dec : 0.f;
            unsigned int wpair;
            asm("v_cvt_pk_bf16_f32 %0, %1, %2" : "=v"(wpair) : "v"(w0), "v"(w1));
            int base = t2 << 3;
            uint4 A0 = Ash[base | ((0 + t2) & 7)];
            uint4 A1 = Ash[base | ((1 + t2) & 7)];
            uint4 A2 = Ash[base | ((2 + t2) & 7)];
            uint4 A3 = Ash[base | ((3 + t2) & 7)];
            uint4 A4 = Ash[base | ((4 + t2) & 7)];
            uint4 A5 = Ash[base | ((5 + t2) & 7)];
            uint4 A6 = Ash[base | ((6 + t2) & 7)];
            uint4 A7 = Ash[base | ((7 + t2) & 7)];
            dot2(acc[0],  A0.x, wpair); dot2(acc[1],  A0.y, wpair);
            dot2(acc[2],  A0.z, wpair); dot2(acc[3],  A0.w, wpair);
            dot2(acc[4],  A1.x, wpair); dot2(acc[5],  A1.y, wpair);
            dot2(acc[6],  A1.z, wpair); dot2(acc[7],  A1.w, wpair);
            dot2(acc[8],  A2.x, wpair); dot2(acc[9],  A2.y, wpair);
            dot2(acc[10], A2.z, wpair); dot2(acc[11], A2.w, wpair);
            dot2(acc[12], A3.x, wpair); dot2(acc[13], A3.y, wpair);
            dot2(acc[14], A3.z, wpair); dot2(acc[15], A3.w, wpair);
            dot2(acc[16], A4.x, wpair); dot2(acc[17], A4.y, wpair);
            dot2(acc[18], A4.z, wpair); dot2(acc[19], A4.w, wpair);
            dot2(acc[20], A5.x, wpair); dot2(acc[21], A5.y, wpair);
            dot2(acc[22], A5.z, wpair); dot2(acc[23], A5.w, wpair);
            dot2(acc[24], A6.x, wpair); dot2(acc[25], A6.y, wpair);
            dot2(acc[26], A6.z, wpair); dot2(acc[27], A6.w, wpair);
            dot2(acc[28], A7.x, wpair); dot2(acc[29], A7.y, wpair);
            dot2(acc[30], A7.z, wpair); dot2(acc[31], A7.w, wpair);
        }
    }
    if (val) {
        unsigned short* PB = (unsigned short*)(g_buf + OFF_PART)
                             + ((size_t)(b * 2 + half) * 5056 + v) * 512 + og * 32;
        unsigned int w[16];
        #pragma unroll
        for (int c2 = 0; c2 < 16; ++c2)
            w[c2] = (unsigned int)f2bf(acc[c2 * 2]) |
                    ((unsigned int)f2bf(acc[c2 * 2 + 1]) << 16);
        uint4* dst = (uint4*)PB;
        dst[0] = make_uint4(w[0],  w[1],  w[2],  w[3]);
        dst[1] = make_uint4(w[4],  w[5],  w[6],  w[7]);
        dst[2] = make_uint4(w[8],  w[9],  w[10], w[11]);
        dst[3] = make_uint4(w[12], w[13], w[14], w[15]);
    }
}

#define MFMA16(a, b, c) __builtin_amdgcn_mfma_f32_16x16x32_bf16(a, b, c, 0, 0, 0)

// ---------- q1: valid pixels only; fuses bf16-partial combine + bias + relu ----------
__global__ __launch_bounds__(256) void k_q1m(const float* __restrict__ bias,
                                             const float* __restrict__ b3d) {
    __shared__ uint4 As[2048];
    __shared__ int qmap[32];
    const unsigned short* Bw = (const unsigned short*)(g_buf + OFF_WQ1B);
    unsigned short* P1 = (unsigned short*)(g_buf + OFF_P1);
    int m0 = blockIdx.x * 32, b = blockIdx.y;
    int tid = threadIdx.x;
    if (tid < 32) {
        int v = m0 + tid; if (v >= NVALID) v = NVALID - 1;
        int i = (int)(100.5 - sqrt(10100.25 - 2.0 * (double)v));
        if (i < 0) i = 0; if (i > 99) i = 99;
        while (100 * (i + 1) - ((i + 1) * i) / 2 <= v && i < 99) ++i;
        while (100 * i - (i * (i - 1)) / 2 > v && i > 0) --i;
        int j = i + (v - (100 * i - (i * (i - 1)) / 2));
        qmap[tid] = i * 100 + j;
    }
    __syncthreads();
    const unsigned short* PB = (const unsigned short*)(g_buf + OFF_PART);
    const size_t PSET = (size_t)5056 * 512;    // ush per partial set
    for (int idx = tid; idx < 2048; idx += 256) {
        int px = idx >> 6, ch = idx & 63;      // ch = octet of channels
        int vr = m0 + px; if (vr >= NVALID) vr = NVALID - 1;
        size_t base = ((size_t)(b * 2) * 5056 + vr) * 512 + ch * 8;
        uint4 s4 = *(const uint4*)(PB + base);
        uint4 t4 = *(const uint4*)(PB + base + PSET);
        const float* bb = b3d + ch * 8;
        unsigned int su[4] = {s4.x, s4.y, s4.z, s4.w};
        unsigned int tu[4] = {t4.x, t4.y, t4.z, t4.w};
        unsigned int w[4];
        #pragma unroll
        for (int wd = 0; wd < 4; ++wd) {
            float x0 = fmaxf(bf2f((unsigned short)su[wd]) +
                             bf2f((unsigned short)tu[wd]) + bb[wd * 2], 0.f);
            float x1 = fmaxf(bf2f((unsigned short)(su[wd] >> 16)) +
                             bf2f((unsigned short)(tu[wd] >> 16)) + bb[wd * 2 + 1], 0.f);
            w[wd] = (unsigned int)f2bf(x0) | ((unsigned int)f2bf(x1) << 16);
        }
        int ch2 = ch ^ (px & 7) ^ (((px >> 3) & 1) << 3);
        As[px * 64 + ch2] = make_uint4(w[0], w[1], w[2], w[3]);
    }
    __syncthreads();
    int wv = tid >> 6, lane = tid & 63, r = lane & 15, g = lane >> 4;
    int q0 = wv * 32;
    f32x4 acc[2][2] = {{{0.f,0.f,0.f,0.f},{0.f,0.f,0.f,0.f}},{{0.f,0.f,0.f,0.f},{0.f,0.f,0.f,0.f}}};
    bf16x8 Bb[4][2], Aa[2][2];
#define Q1_LB(slot, it_) { const unsigned short* bp = Bw + (size_t)(q0 + r) * 512 + (it_) * 32 + g * 8; \
    Bb[slot][0] = *(const bf16x8*)bp; Bb[slot][1] = *(const bf16x8*)(bp + 16 * 512); }
#define Q1_LA(slot, it_) { int ch = (it_) * 4 + g; \
    int px0 = r, px1 = 16 + r; \
    Aa[slot][0] = *(const bf16x8*)&As[px0 * 64 + (ch ^ (px0 & 7) ^ (((px0 >> 3) & 1) << 3))]; \
    Aa[slot][1] = *(const bf16x8*)&As[px1 * 64 + (ch ^ (px1 & 7) ^ (((px1 >> 3) & 1) << 3))]; }
    Q1_LB(0, 0); Q1_LB(1, 1); Q1_LB(2, 2); Q1_LA(0, 0);
    #pragma unroll
    for (int it = 0; it < 16; ++it) {
        if (it + 3 < 16) Q1_LB((it + 3) & 3, it + 3);
        if (it + 1 < 16) Q1_LA((it + 1) & 1, it + 1);
        int s = it & 3, sa = it & 1;
        acc[0][0] = MFMA16(Aa[sa][0], Bb[s][0], acc[0][0]);
        acc[0][1] = MFMA16(Aa[sa][0], Bb[s][1], acc[0][1]);
        acc[1][0] = MFMA16(Aa[sa][1], Bb[s][0], acc[1][0]);
        acc[1][1] = MFMA16(Aa[sa][1], Bb[s][1], acc[1][1]);
    }
    float bi0 = bias[q0 + r], bi1 = bias[q0 + 16 + r];
    unsigned short* Pout = P1 + (size_t)b * PSTRIDE;
    #pragma unroll
    for (int mt = 0; mt < 2; ++mt)
        #pragma unroll
        for (int reg = 0; reg < 4; ++reg) {
            int px = mt * 16 + g * 4 + reg;
            if (m0 + px < NVALID) {
                int q = qmap[px];
                int i = q / 100, j = q - i * 100;
                size_t base = (size_t)((i + 1) * PADW + j + 1) * H2C;
                Pout[base + q0 + r]      = f2bf(fmaxf(acc[mt][0][reg] + bi0, 0.f));
                Pout[base + q0 + 16 + r] = f2bf(fmaxf(acc[mt][1][reg] + bi1, 0.f));
            }
        }
}

// ---------- 3x3 conv 128->128, M=64 (2 output rows/block); FQ4: fused q4+sigmoid ----------
template<int FQ4>
__global__ __launch_bounds__(256) void k_c3m2(int in_off, int w_off,
                                              const float* __restrict__ bias,
                                              int out_off,
                                              const float* __restrict__ wq4,
                                              const float* __restrict__ bq4,
                                              float* __restrict__ out) {
    __shared__ uint4 As[2176];                 // 4 rows x 34 px x 16 oct
    const unsigned short* Pin = (const unsigned short*)(g_buf + in_off);
    const unsigned short* wB  = (const unsigned short*)(g_buf + w_off);
    int jt = blockIdx.x, y = blockIdx.y, b = blockIdx.z;
    int i0 = y * 2;
    int j0 = (jt == 3) ? 68 : jt * 32;
    int tid = threadIdx.x;
    const unsigned short* Ab = Pin + (size_t)b * PSTRIDE;
    for (int idx = tid; idx < 2176; idx += 256) {
        int row = idx / 544, rem = idx - row * 544;
        int px = rem >> 4, ch = rem & 15;
        int ch2 = ch ^ (px & 7) ^ (((px >> 3) & 1) << 3);
        As[(row * 34 + px) * 16 + ch2] =
            *(const uint4*)(Ab + (size_t)((i0 + row) * PADW + j0 + px) * H2C + ch * 8);
    }
    __syncthreads();
    int wv = tid >> 6, lane = tid & 63, r = lane & 15, g = lane >> 4;
    int q0 = wv * 32;
    f32x4 acc[2][2][2];
    #pragma unroll
    for (int a = 0; a < 2; ++a)
        #pragma unroll
        for (int m = 0; m < 2; ++m)
            #pragma unroll
            for (int h = 0; h < 2; ++h) acc[a][m][h] = (f32x4){0.f, 0.f, 0.f, 0.f};
    bf16x8 Bb[4][2], Aa[2][4];
#define C2_LB(slot, it_) { int tap = (it_) >> 2, cc = (it_) & 3; \
    const unsigned short* bp = wB + (size_t)(q0 + r) * 1152 + tap * 128 + cc * 32 + g * 8; \
    Bb[slot][0] = *(const bf16x8*)bp; Bb[slot][1] = *(const bf16x8*)(bp + 16 * 1152); }
#define C2_LA(slot, it_) { int tap = (it_) >> 2, cc = (it_) & 3; \
    int ky = tap / 3, kx = tap - ky * 3; int ch = cc * 4 + g; \
    int px0 = r + kx, px1 = 16 + r + kx; \
    Aa[slot][0] = *(const bf16x8*)&As[(ky * 34 + px0) * 16 + (ch ^ (px0 & 7) ^ (((px0 >> 3) & 1) << 3))]; \
    Aa[slot][1] = *(const bf16x8*)&As[(ky * 34 + px1) * 16 + (ch ^ (px1 & 7) ^ (((px1 >> 3) & 1) << 3))]; \
    Aa[slot][2] = *(const bf16x8*)&As[((ky + 1) * 34 + px0) * 16 + (ch ^ (px0 & 7) ^ (((px0 >> 3) & 1) << 3))]; \
    Aa[slot][3] = *(const bf16x8*)&As[((ky + 1) * 34 + px1) * 16 + (ch ^ (px1 & 7) ^ (((px1 >> 3) & 1) << 3))]; }
    C2_LB(0, 0); C2_LB(1, 1); C2_LB(2, 2); C2_LA(0, 0);
    #pragma unroll
    for (int it = 0; it < 36; ++it) {
        if (it + 3 < 36) C2_LB((it + 3) & 3, it + 3);
        if (it + 1 < 36) C2_LA((it + 1) & 1, it + 1);
        int s = it & 3, sa = it & 1;
        acc[0][0][0] = MFMA16(Aa[sa][0], Bb[s][0], acc[0][0][0]);
        acc[0][0][1] = MFMA16(Aa[sa][0], Bb[s][1], acc[0][0][1]);
        acc[0][1][0] = MFMA16(Aa[sa][1], Bb[s][0], acc[0][1][0]);
        acc[0][1][1] = MFMA16(Aa[sa][1], Bb[s][1], acc[0][1][1]);
        acc[1][0][0] = MFMA16(Aa[sa][2], Bb[s][0], acc[1][0][0]);
        acc[1][0][1] = MFMA16(Aa[sa][2], Bb[s][1], acc[1][0][1]);
        acc[1][1][0] = MFMA16(Aa[sa][3], Bb[s][0], acc[1][1][0]);
        acc[1][1][1] = MFMA16(Aa[sa][3], Bb[s][1], acc[1][1][1]);
    }
    float bi0 = bias[q0 + r], bi1 = bias[q0 + 16 + r];
    if constexpr (!FQ4) {
        unsigned short* Ob = (unsigned short*)(g_buf + out_off) + (size_t)b * PSTRIDE;
        #pragma unroll
        for (int orow = 0; orow < 2; ++orow)
            #pragma unroll
            for (int mt = 0; mt < 2; ++mt)
                #pragma unroll
                for (int reg = 0; reg < 4; ++reg) {
                    int j = j0 + mt * 16 + g * 4 + reg;
                    size_t base = (size_t)((i0 + orow + 1) * PADW + j + 1) * H2C;
                    Ob[base + q0 + r]      = f2bf(fmaxf(acc[orow][mt][0][reg] + bi0, 0.f));
                    Ob[base + q0 + 16 + r] = f2bf(fmaxf(acc[orow][mt][1][reg] + bi1, 0.f));
                }
    } else {
        __shared__ float part[4][2][2][32];
        float w40a = wq4[q0 + r],       w40b = wq4[q0 + 16 + r];
        float w41a = wq4[128 + q0 + r], w41b = wq4[128 + q0 + 16 + r];
        #pragma unroll
        for (int orow = 0; orow < 2; ++orow)
            #pragma unroll
            for (int mt = 0; mt < 2; ++mt)
                #pragma unroll
                for (int reg = 0; reg < 4; ++reg) {
                    float x0 = fmaxf(acc[orow][mt][0][reg] + bi0, 0.f);
                    float x1 = fmaxf(acc[orow][mt][1][reg] + bi1, 0.f);
                    float p0 = x0 * w40a + x1 * w40b;
                    float p1 = x0 * w41a + x1 * w41b;
                    #pragma unroll
                    for (int off = 1; off < 16; off <<= 1) {
                        p0 += __shfl_xor(p0, off);
                        p1 += __shfl_xor(p1, off);
                    }
                    if (r == 0) {
                        int px = mt * 16 + g * 4 + reg;
                        part[wv][orow][0][px] = p0;
                        part[wv][orow][1][px] = p1;
                    }
                }
        __syncthreads();
        if (tid < 128) {
            int px = tid & 31, hd = (tid >> 5) & 1, orow = tid >> 6;
            float s = part[0][orow][hd][px] + part[1][orow][hd][px] +
                      part[2][orow][hd][px] + part[3][orow][hd][px] + bq4[hd];
            out[(size_t)(b * 2 + hd) * IJ + (i0 + orow) * 100 + (j0 + px)] =
                1.f / (1.f + expf(-s));
        }
    }
}

extern "C" void kernel_launch(void* const* d_in, const int* in_sizes, int n_in,
                              void* d_out, int out_size, void* d_ws, size_t ws_size,
                              hipStream_t stream) {
    const float* x   = (const float*)d_in[0];
    const float* wb1 = (const float*)d_in[1];  const float* bb1 = (const float*)d_in[2];
    const float* wb2 = (const float*)d_in[3];  const float* bb2 = (const float*)d_in[4];
    const float* ws1 = (const float*)d_in[5];  const float* bs1 = (const float*)d_in[6];
    const float* ws2 = (const float*)d_in[7];  const float* bs2 = (const float*)d_in[8];
    const float* we1 = (const float*)d_in[9];  const float* be1 = (const float*)d_in[10];
    const float* we2 = (const float*)d_in[11]; const float* be2 = (const float*)d_in[12];
    const float* wp  = (const float*)d_in[13]; const float* bp  = (const float*)d_in[14];
    const float* w3d = (const float*)d_in[15]; const float* b3d = (const float*)d_in[16];
    const float* wq1 = (const float*)d_in[17]; const float* bq1 = (const float*)d_in[18];
    const float* wq2 = (const float*)d_in[19]; const float* bq2 = (const float*)d_in[20];
    const float* wq3 = (const float*)d_in[21]; const float* bq3 = (const float*)d_in[22];
    const float* wq4 = (const float*)d_in[23]; const float* bq4 = (const float*)d_in[24];
    float* out = (float*)d_out;

    k_prepw<<<512 + (PREP_IDS + 255) / 256, 256, 0, stream>>>(wq1, wq2, wq3, x, b3d, bq1, w3d);
    k_conv_t<100, 64, 400><<<400, 256, 0, stream>>>(OFF_XT, wb1, bb1, OFF_H1);
    k_conv_t<64, 64, 256><<<400, 256, 0, stream>>>(OFF_H1, wb2, bb2, OFF_H2);
    k_sepf<<<1200, 256, 0, stream>>>(ws1, bs1, we1, be1, wp, bp);
    k_amfh<<<1792 + Q1F_BLKS + 2, 256, 0, stream>>>(ws2, bs2, we2, be2, out);
    k_bm2<<<dim3(20, 16, 4), 256, 0, stream>>>();
    k_q1m<<<dim3((NVALID + 31) / 32, 2), 256, 0, stream>>>(bq1, b3d);
    k_c3m2<0><<<dim3(4, 50, 2), 256, 0, stream>>>(OFF_P1, OFF_WQ2B, bq2, OFF_P2,
                                                  nullptr, nullptr, nullptr);
    k_c3m2<1><<<dim3(4, 50, 2), 256, 0, stream>>>(OFF_P2, OFF_WQ3B, bq3, 0,
                                                  wq4, bq4, out);
}

// Round 25
// 196.109 us; speedup vs baseline: 1.2896x; 1.0331x over previous
//
#include <hip/hip_runtime.h>
#include <hip/hip_bf16.h>
#include <math.h>

#define TT  100
#define CIN 400
#define H1  256
#define NS  32
#define NP  96
#define H3  512
#define H2C 128
#define BB  2
#define IJ  10000
#define NVALID 5050
#define NINVAL 4950
#define PADW 102
#define PPIX 10432
#define PSTRIDE (PPIX * H2C)

typedef __attribute__((ext_vector_type(8))) short bf16x8;
typedef __attribute__((ext_vector_type(4))) float f32x4;

// ---- static scratch (float units) ----
#define OFF_XT   0
#define OFF_H1   80000
#define OFF_H2   131200
#define OFF_SB   182400
#define OFF_EB   233600
#define OFF_PF   284800
#define OFF_ATB  336000      // bf16 pairs ATb[b][16 og32][3200 m][8 quad-rotated][4ch][2]
#define OFF_P1   8732800
#define OFF_P2   10068096
#define OFF_CINV 11403392    // uint[64]: c_inv as bf16 pairs
#define OFF_WQ1B 12683392
#define OFF_WQ2B 12716160
#define OFF_WQ3B 12789888
#define OFF_DESC 12863616    // u32 [96][5056] valid-rank indexed
#define OFF_PFT  13846656    // bf16 [b][112][256]
#define OFF_W3B  13875328    // bf16 [n][o][c]
#define OFF_PART 15972480    // bf16 [(b*2+half)][5056 v][512 ch]
#define G_TOTAL  21149824

__device__ __align__(16) float g_buf[G_TOTAL];

__device__ inline unsigned short f2bf(float f) {
    __hip_bfloat16 h = __float2bfloat16(f);
    return *(unsigned short*)&h;
}
__device__ inline float bf2f(unsigned short u) {
    union { unsigned int i; float f; } v; v.i = ((unsigned int)u) << 16; return v.f;
}
__device__ inline void dot2(float& acc, unsigned int a, unsigned int w) {
    asm("v_dot2_f32_bf16 %0, %1, %2, %0" : "+v"(acc) : "v"(a), "v"(w));
}
// async global->LDS, 16B per lane; lds dest = wave-uniform base + lane*16
__device__ inline void gload_lds16(const void* g, void* l) {
    __builtin_amdgcn_global_load_lds(
        (const __attribute__((address_space(1))) unsigned int*)g,
        (__attribute__((address_space(3))) unsigned int*)l, 16, 0, 0);
}

// ---------- merged prep: w3prep blocks [0,512) + element-wise prep ----------
#define PREP_IDS (65536 + 147456 + 147456 + 51712 + 5056 + BB * TT * CIN + BB * 12 * 256 + 128)
__global__ __launch_bounds__(256) void k_prepw(
        const float* __restrict__ wq1, const float* __restrict__ wq2,
        const float* __restrict__ wq3, const float* __restrict__ x,
        const float* __restrict__ b3d, const float* __restrict__ bq1,
        const float* __restrict__ w3d) {
    __shared__ float tile[8192];
    int tid = threadIdx.x;
    if (blockIdx.x < 512) {   // w3b[n][o][c] bf16 from w3d[o][c][n]
        int o = blockIdx.x;
        const float* src = w3d + o * 8192;
        for (int idx = tid; idx < 8192; idx += 256) tile[idx] = src[idx];
        __syncthreads();
        int n = tid & 31, ch = tid >> 5;
        unsigned short* w3b = (unsigned short*)(g_buf + OFF_W3B);
        unsigned int w[16];
        #pragma unroll
        for (int c2 = 0; c2 < 16; ++c2) {
            int c = ch * 32 + c2 * 2;
            w[c2] = (unsigned int)f2bf(tile[c * 32 + n]) |
                    ((unsigned int)f2bf(tile[(c + 1) * 32 + n]) << 16);
        }
        uint4* dst = (uint4*)(w3b + ((size_t)n * 512 + o) * 256 + ch * 32);
        dst[0] = make_uint4(w[0], w[1], w[2], w[3]);
        dst[1] = make_uint4(w[4], w[5], w[6], w[7]);
        dst[2] = make_uint4(w[8], w[9], w[10], w[11]);
        dst[3] = make_uint4(w[12], w[13], w[14], w[15]);
        return;
    }
    int id = (blockIdx.x - 512) * 256 + tid;
    if (id < 65536) {
        ((unsigned short*)(g_buf + OFF_WQ1B))[id] = f2bf(wq1[id]);
        return;
    }
    id -= 65536;
    if (id < 147456) {
        int q = id / 1152, k = id % 1152, tap = k >> 7, c = k & 127;
        ((unsigned short*)(g_buf + OFF_WQ2B))[id] = f2bf(wq2[(q * 128 + c) * 9 + tap]);
        return;
    }
    id -= 147456;
    if (id < 147456) {
        int q = id / 1152, k = id % 1152, tap = k >> 7, c = k & 127;
        ((unsigned short*)(g_buf + OFF_WQ3B))[id] = f2bf(wq3[(q * 128 + c) * 9 + tap]);
        return;
    }
    id -= 147456;
    if (id < 51712) {   // halo zero
        int c = id & 31;
        int h = (id >> 5) % 404;
        int bb = ((id >> 5) / 404) & 1;
        int buf = id / 25856;
        int pix;
        if (h < 102) pix = h;
        else if (h < 204) pix = 101 * PADW + (h - 102);
        else { int q = h - 204; pix = (1 + (q >> 1)) * PADW + ((q & 1) ? 101 : 0); }
        unsigned short* P = (unsigned short*)(g_buf + (buf ? OFF_P2 : OFF_P1))
                            + (size_t)bb * PSTRIDE + (size_t)pix * H2C;
        ((uint2*)P)[c] = make_uint2(0u, 0u);
        return;
    }
    id -= 51712;
    if (id < 5056) {   // desc: one thread per rank v, loop over all k
        int v = id;
        bool valid = (v < NVALID);
        double xmn = 0.0, plen = 0.0;
        if (valid) {
            int i = (int)(100.5 - sqrt(10100.25 - 2.0 * (double)v));
            if (i < 0) i = 0; if (i > 99) i = 99;
            while (100 * (i + 1) - ((i + 1) * i) / 2 <= v && i < 99) ++i;
            while (100 * i - (i * (i - 1)) / 2 > v && i > 0) --i;
            int j = i + (v - (100 * i - (i * (i - 1)) / 2));
            double len = (double)(j - i + 2);
            xmn = (double)i - 0.5 * len;
            double xmx = (double)(j + 1) + 0.5 * len;
            plen = (xmx - xmn) / 95.0;
        }
        unsigned int* dout = (unsigned int*)(g_buf + OFF_DESC);
        for (int k = 0; k < NP; ++k) {
            unsigned int nb = (unsigned int)((k / 3) * 100);
            unsigned int d = nb | (2u << 12);
            if (valid) {
                double s = __dadd_rn(xmn, __dmul_rn(plen, (double)k));
                double tr = trunc(s);
                double dec = s - tr;
                int dn = (int)tr;
                int up = (int)ceil(s);
                bool okd = (unsigned)dn < (unsigned)TT;
                bool oku = (unsigned)up < (unsigned)TT;
                if (!okd) d = nb | (2u << 12);
                else if (oku && up == dn + 1) {
                    unsigned int dfx = (unsigned int)__double2int_rn(dec * 65535.0);
                    d = (nb + dn) | (dfx << 16);
                } else if (oku) {
                    d = (nb + dn) | (1u << 12);
                } else {
                    unsigned int dfx = (unsigned int)__double2int_rn(dec * 65535.0);
                    d = (nb + dn) | (1u << 12) | (dfx << 16);
                }
            }
            dout[(size_t)k * 5056 + v] = d;
        }
        return;
    }
    id -= 5056;
    if (id < BB * TT * CIN) {   // x transpose
        int c = id % CIN, t = (id / CIN) % TT, b = id / (CIN * TT);
        g_buf[OFF_XT + (b * CIN + c) * TT + t] = x[id];
        return;
    }
    id -= BB * TT * CIN;
    if (id < BB * 12 * 256) {   // zero pfT pad rows
        int c = id & 255, tp = (id >> 8) % 12, b = id / (12 * 256);
        ((unsigned short*)(g_buf + OFF_PFT))[((size_t)b * 112 + 100 + tp) * 256 + c] = 0;
        return;
    }
    id -= BB * 12 * 256;
    if (id < 128) {   // c_inv[q] = relu(wq1 . relu(b3d) + bq1)
        int q = id;
        float acc = bq1[q];
        const float* wr = wq1 + q * 512;
        #pragma unroll 8
        for (int c = 0; c < 512; ++c) acc = fmaf(wr[c], fmaxf(b3d[c], 0.f), acc);
        acc = fmaxf(acc, 0.f);
        float accO = __shfl_xor(acc, 1);
        if ((id & 1) == 0)
            ((unsigned int*)(g_buf + OFF_CINV))[id >> 1] =
                (unsigned int)f2bf(acc) | ((unsigned int)f2bf(accO) << 16);
    }
}

// ---------- conv1d k=3 pad=1 + relu; wave-split x4 over ci (coalescing kept) ----------
template<int IPG, int OPG, int CINTOT>
__global__ __launch_bounds__(256) void k_conv_t(int in_off, const float* __restrict__ w,
                                                const float* __restrict__ bias, int out_off) {
    __shared__ float part[3][64];
    int tid = threadIdx.x;
    int qtr = tid >> 6, lid = tid & 63;
    int outp = blockIdx.x * 64 + lid;             // grid exact: total/64 blocks
    int t = outp % TT, o = (outp / TT) % H1, b = outp / (TT * H1);
    const float* ip = g_buf + in_off
                    + (b * CINTOT + (o / OPG) * IPG + qtr * (IPG / 4)) * TT + t;
    const float* wp = w + o * IPG * 3 + qtr * (IPG / 4) * 3;
    float a0 = 0.f, a1 = 0.f, a2 = 0.f;
    bool t0 = (t > 0), t1 = (t < TT - 1);
    #pragma unroll 4
    for (int ci = 0; ci < IPG / 4; ++ci) {
        float v0 = t0 ? ip[ci * TT - 1] : 0.f;
        float v1 = ip[ci * TT];
        float v2 = t1 ? ip[ci * TT + 1] : 0.f;
        a0 = fmaf(v0, wp[ci * 3 + 0], a0);
        a1 = fmaf(v1, wp[ci * 3 + 1], a1);
        a2 = fmaf(v2, wp[ci * 3 + 2], a2);
    }
    float a = a0 + a1 + a2;
    if (qtr) part[qtr - 1][lid] = a;
    __syncthreads();
    if (!qtr)
        g_buf[out_off + outp] =
            fmaxf(a + part[0][lid] + part[1][lid] + part[2][lid] + bias[o], 0.f);
}

// ---------- merged s/e convs + pf conv; wave-split x4 ----------
__global__ __launch_bounds__(256) void k_sepf(
        const float* __restrict__ ws1, const float* __restrict__ bs1,
        const float* __restrict__ we1, const float* __restrict__ be1,
        const float* __restrict__ wp, const float* __restrict__ bp) {
    __shared__ float part[3][64];
    int blk = blockIdx.x;
    int tid = threadIdx.x;
    int qtr = tid >> 6, lid = tid & 63;
    if (blk < 1600) {   // s (0-799) / e (800-1599), grouped 64-ch: 16 ci per quarter
        int sec = blk >= 800;
        int outp = (blk - sec * 800) * 64 + lid;
        const float* w  = sec ? we1 : ws1;
        const float* bi = sec ? be1 : bs1;
        int out_off = sec ? OFF_EB : OFF_SB;
        int t = outp % TT, o = (outp / TT) % H1, b = outp / (TT * H1);
        const float* ip = g_buf + OFF_H2 + (b * H1 + (o / 64) * 64 + qtr * 16) * TT + t;
        const float* wpp = w + o * 64 * 3 + qtr * 16 * 3;
        float a0 = 0.f, a1 = 0.f, a2 = 0.f;
        bool tl = (t > 0), th = (t < TT - 1);
        #pragma unroll 4
        for (int ci = 0; ci < 16; ++ci) {
            float v0 = tl ? ip[ci * TT - 1] : 0.f;
            float v1 = ip[ci * TT];
            float v2 = th ? ip[ci * TT + 1] : 0.f;
            a0 = fmaf(v0, wpp[ci * 3 + 0], a0);
            a1 = fmaf(v1, wpp[ci * 3 + 1], a1);
            a2 = fmaf(v2, wpp[ci * 3 + 2], a2);
        }
        float a = a0 + a1 + a2;
        if (qtr) part[qtr - 1][lid] = a;
        __syncthreads();
        if (!qtr)
            g_buf[out_off + outp] =
                fmaxf(a + part[0][lid] + part[1][lid] + part[2][lid] + bi[o], 0.f);
    } else {            // pf conv (256 ch): 64 ci per quarter
        int outp = (blk - 1600) * 64 + lid;
        int t = outp % TT, o = (outp / TT) % H1, b = outp / (TT * H1);
        const float* ip = g_buf + OFF_H2 + (b * H1 + qtr * 64) * TT + t;
        const float* wpp = wp + o * H1 * 3 + qtr * 64 * 3;
        float a0 = 0.f, a1 = 0.f, a2 = 0.f;
        bool tl = (t > 0), th = (t < TT - 1);
        #pragma unroll 4
        for (int ci = 0; ci < 64; ++ci) {
            float v0 = tl ? ip[ci * TT - 1] : 0.f;
            float v1 = ip[ci * TT];
            float v2 = th ? ip[ci * TT + 1] : 0.f;
            a0 = fmaf(v0, wpp[ci * 3 + 0], a0);
            a1 = fmaf(v1, wpp[ci * 3 + 1], a1);
            a2 = fmaf(v2, wpp[ci * 3 + 2], a2);
        }
        float a = a0 + a1 + a2;
        if (qtr) part[qtr - 1][lid] = a;
        __syncthreads();
        if (!qtr)
            ((unsigned short*)(g_buf + OFF_PFT))[((size_t)b * 112 + t) * 256 + o] =
                f2bf(fmaxf(a + part[0][lid] + part[1][lid] + part[2][lid] + bp[o], 0.f));
    }
}

// ---------- merged: Am (MFMA A-build, quad-rotated layout) + q1f + heads ----------
#define Q1F_BLKS ((BB * NINVAL * 16 + 255) / 256)
__global__ __launch_bounds__(256) void k_amfh(
        const float* __restrict__ ws2, const float* __restrict__ bs2,
        const float* __restrict__ we2, const float* __restrict__ be2,
        float* __restrict__ out) {
    int blk = blockIdx.x;
    if (blk < 1792) {   // k_Am: ATb pairs, quad-rotated: ch c of row m at quad ((c>>2)+m)&7
        int mt = blk % 7, nt = (blk / 7) % 4, bn = blk / 28;
        int b = bn >> 5, n = bn & 31;
        int wv = threadIdx.x >> 6, lane = threadIdx.x & 63;
        int r = lane & 15, g = lane >> 4;
        const unsigned short* ap = (const unsigned short*)(g_buf + OFF_PFT)
                                   + ((size_t)b * 112 + mt * 16 + r) * 256 + g * 8;
        const unsigned short* bp = (const unsigned short*)(g_buf + OFF_W3B)
                                   + ((size_t)n * 512 + nt * 128 + wv * 32 + r) * 256 + g * 8;
        f32x4 acc0 = {0.f, 0.f, 0.f, 0.f}, acc1 = {0.f, 0.f, 0.f, 0.f};
        #pragma unroll
        for (int ks = 0; ks < 8; ++ks) {
            bf16x8 a  = *(const bf16x8*)(ap + ks * 32);
            bf16x8 b0 = *(const bf16x8*)(bp + ks * 32);
            bf16x8 b1 = *(const bf16x8*)(bp + 16 * 256 + ks * 32);
            acc0 = __builtin_amdgcn_mfma_f32_16x16x32_bf16(a, b0, acc0, 0, 0, 0);
            acc1 = __builtin_amdgcn_mfma_f32_16x16x32_bf16(a, b1, acc1, 0, 0, 0);
        }
        unsigned short* ATb = (unsigned short*)(g_buf + OFF_ATB);
        int og = nt * 4 + wv;
        size_t gb = (size_t)(b * 16 + og) * 3200;
        int c0 = r, c1 = 16 + r;
        int q0c = c0 >> 2, o0c = (c0 & 3) * 2;
        int q1c = c1 >> 2, o1c = (c1 & 3) * 2;
        #pragma unroll
        for (int reg = 0; reg < 4; ++reg) {
            int t = mt * 16 + g * 4 + reg;
            if (t < TT) {
                int m = n * 100 + t;
                unsigned short v0 = f2bf(acc0[reg] * (1.f / 3.f));
                unsigned short v1 = f2bf(acc1[reg] * (1.f / 3.f));
                size_t row = (gb + m) * 64;
                size_t base0 = row + (size_t)((((q0c + m) & 7) << 3) + o0c);
                size_t base1 = row + (size_t)((((q1c + m) & 7) << 3) + o1c);
                ATb[base0] = v0;
                ATb[base1] = v1;
                if (t > 0) {
                    size_t rowp = (gb + m - 1) * 64;
                    ATb[rowp + (size_t)((((q0c + m - 1) & 7) << 3) + o0c) + 1] = v0;
                    ATb[rowp + (size_t)((((q1c + m - 1) & 7) << 3) + o1c) + 1] = v1;
                }
                if (t == TT - 1) {
                    ATb[base0 + 1] = 0;
                    ATb[base1 + 1] = 0;
                }
            }
        }
        return;
    }
    if (blk < 1792 + Q1F_BLKS) {   // q1f: invalid (i>j) pixels only, rank-indexed
        int id = (blk - 1792) * 256 + threadIdx.x;
        if (id >= BB * NINVAL * 16) return;
        int c = id & 15;
        int rr = (id >> 4) % NINVAL;
        int b = id / (16 * NINVAL);
        int i = (int)((1.0 + sqrt(1.0 + 8.0 * (double)rr)) * 0.5);
        if (i < 1) i = 1; if (i > 99) i = 99;
        while ((i * (i - 1)) / 2 > rr) --i;
        while (((i + 1) * i) / 2 <= rr) ++i;
        int j = rr - (i * (i - 1)) / 2;        // j in [0, i) => i > j
        uint4 w = ((const uint4*)(g_buf + OFF_CINV))[c];
        unsigned short* P1 = (unsigned short*)(g_buf + OFF_P1) + (size_t)b * PSTRIDE;
        *(uint4*)(P1 + (size_t)((i + 1) * PADW + j + 1) * H2C + c * 8) = w;
        return;
    }
    {   // heads
        int which = blk - (1792 + Q1F_BLKS);
        const float* w  = which ? we2 : ws2;
        const float* bi = which ? be2 : bs2;
        int in_off = which ? OFF_EB : OFF_SB;
        int id = threadIdx.x;
        if (id >= BB * TT) return;
        int t = id % TT, b = id / TT;
        const float* ip = g_buf + in_off + b * H1 * TT + t;
        float acc = bi[0];
        for (int c = 0; c < H1; ++c) acc = fmaf(ip[c * TT], w[c], acc);
        out[40000 + which * 200 + id] = 1.f / (1.f + expf(-acc));
    }
}

// ---------- BM gather: 32 ch/block, k-split x2, bf16 partials, async LDS stage ----------
__global__ __launch_bounds__(256) void k_bm2() {
    __shared__ uint4 Ash[1600];                 // 200 rows x 8 quads (rotation baked in global)
    int qt = blockIdx.x, og = blockIdx.y, z = blockIdx.z;
    int b = z >> 1, half = z & 1;
    int tid = threadIdx.x;
    int lane = tid & 63, wv4 = tid >> 6;
    int v = qt * 256 + tid;
    bool val = (v < NVALID);
    int vv = val ? v : 0;
    const unsigned int* desc = (const unsigned int*)(g_buf + OFF_DESC);
    const uint4* src = (const uint4*)((const unsigned short*)(g_buf + OFF_ATB)
                                      + (size_t)(b * 16 + og) * 3200 * 64);
    float acc[32];
    #pragma unroll
    for (int c = 0; c < 32; ++c) acc[c] = 0.f;

    for (int st = half * 8; st < half * 8 + 8; ++st) {
        __syncthreads();
        for (int idx0 = wv4 * 64; idx0 < 1600; idx0 += 256)
            gload_lds16(src + st * 1600 + idx0 + lane, (void*)&Ash[idx0]);
        __syncthreads();
        #pragma unroll
        for (int kk = 0; kk < 6; ++kk) {
            unsigned int d = desc[(size_t)(st * 6 + kk) * 5056 + vv];
            int t2 = (int)(d & 0xFFFu) - st * 200;
            unsigned int mode = (d >> 12) & 3u;
            float dec = (float)(d >> 16) * (1.f / 65535.f);
            float w0 = (mode == 2u) ? 0.f : 1.f - dec;
            float w1 = (mode == 0u) ? dec : 0.f;
            unsigned int wpair;
            asm("v_cvt_pk_bf16_f32 %0, %1, %2" : "=v"(wpair) : "v"(w0), "v"(w1));
            int base = t2 << 3;
            uint4 A0 = Ash[base | ((0 + t2) & 7)];
            uint4 A1 = Ash[base | ((1 + t2) & 7)];
            uint4 A2 = Ash[base | ((2 + t2) & 7)];
            uint4 A3 = Ash[base | ((3 + t2) & 7)];
            uint4 A4 = Ash[base | ((4 + t2) & 7)];
            uint4 A5 = Ash[base | ((5 + t2) & 7)];
            uint4 A6 = Ash[base | ((6 + t2) & 7)];
            uint4 A7 = Ash[base | ((7 + t2) & 7)];
            dot2(acc[0],  A0.x, wpair); dot2(acc[1],  A0.y, wpair);
            dot2(acc[2],  A0.z, wpair); dot2(acc[3],  A0.w, wpair);
            dot2(acc[4],  A1.x, wpair); dot2(acc[5],  A1.y, wpair);
            dot2(acc[6],  A1.z, wpair); dot2(acc[7],  A1.w, wpair);
            dot2(acc[8],  A2.x, wpair); dot2(acc[9],  A2.y, wpair);
            dot2(acc[10], A2.z, wpair); dot2(acc[11], A2.w, wpair);
            dot2(acc[12], A3.x, wpair); dot2(acc[13], A3.y, wpair);
            dot2(acc[14], A3.z, wpair); dot2(acc[15], A3.w, wpair);
            dot2(acc[16], A4.x, wpair); dot2(acc[17], A4.y, wpair);
            dot2(acc[18], A4.z, wpair); dot2(acc[19], A4.w, wpair);
            dot2(acc[20], A5.x, wpair); dot2(acc[21], A5.y, wpair);
            dot2(acc[22], A5.z, wpair); dot2(acc[23], A5.w, wpair);
            dot2(acc[24], A6.x, wpair); dot2(acc[25], A6.y, wpair);
            dot2(acc[26], A6.z, wpair); dot2(acc[27], A6.w, wpair);
            dot2(acc[28], A7.x, wpair); dot2(acc[29], A7.y, wpair);
            dot2(acc[30], A7.z, wpair); dot2(acc[31], A7.w, wpair);
        }
    }
    if (val) {
        unsigned short* PB = (unsigned short*)(g_buf + OFF_PART)
                             + ((size_t)(b * 2 + half) * 5056 + v) * 512 + og * 32;
        unsigned int w[16];
        #pragma unroll
        for (int c2 = 0; c2 < 16; ++c2)
            w[c2] = (unsigned int)f2bf(acc[c2 * 2]) |
                    ((unsigned int)f2bf(acc[c2 * 2 + 1]) << 16);
        uint4* dst = (uint4*)PB;
        dst[0] = make_uint4(w[0],  w[1],  w[2],  w[3]);
        dst[1] = make_uint4(w[4],  w[5],  w[6],  w[7]);
        dst[2] = make_uint4(w[8],  w[9],  w[10], w[11]);
        dst[3] = make_uint4(w[12], w[13], w[14], w[15]);
    }
}

#define MFMA16(a, b, c) __builtin_amdgcn_mfma_f32_16x16x32_bf16(a, b, c, 0, 0, 0)

// ---------- q1: valid pixels only; fuses bf16-partial combine + bias + relu ----------
__global__ __launch_bounds__(256) void k_q1m(const float* __restrict__ bias,
                                             const float* __restrict__ b3d) {
    __shared__ uint4 As[2048];
    __shared__ int qmap[32];
    const unsigned short* Bw = (const unsigned short*)(g_buf + OFF_WQ1B);
    unsigned short* P1 = (unsigned short*)(g_buf + OFF_P1);
    int m0 = blockIdx.x * 32, b = blockIdx.y;
    int tid = threadIdx.x;
    if (tid < 32) {
        int v = m0 + tid; if (v >= NVALID) v = NVALID - 1;
        int i = (int)(100.5 - sqrt(10100.25 - 2.0 * (double)v));
        if (i < 0) i = 0; if (i > 99) i = 99;
        while (100 * (i + 1) - ((i + 1) * i) / 2 <= v && i < 99) ++i;
        while (100 * i - (i * (i - 1)) / 2 > v && i > 0) --i;
        int j = i + (v - (100 * i - (i * (i - 1)) / 2));
        qmap[tid] = i * 100 + j;
    }
    __syncthreads();
    const unsigned short* PB = (const unsigned short*)(g_buf + OFF_PART);
    const size_t PSET = (size_t)5056 * 512;    // ush per partial set
    for (int idx = tid; idx < 2048; idx += 256) {
        int px = idx >> 6, ch = idx & 63;      // ch = octet of channels
        int vr = m0 + px; if (vr >= NVALID) vr = NVALID - 1;
        size_t base = ((size_t)(b * 2) * 5056 + vr) * 512 + ch * 8;
        uint4 s4 = *(const uint4*)(PB + base);
        uint4 t4 = *(const uint4*)(PB + base + PSET);
        const float* bb = b3d + ch * 8;
        unsigned int su[4] = {s4.x, s4.y, s4.z, s4.w};
        unsigned int tu[4] = {t4.x, t4.y, t4.z, t4.w};
        unsigned int w[4];
        #pragma unroll
        for (int wd = 0; wd < 4; ++wd) {
            float x0 = fmaxf(bf2f((unsigned short)su[wd]) +
                             bf2f((unsigned short)tu[wd]) + bb[wd * 2], 0.f);
            float x1 = fmaxf(bf2f((unsigned short)(su[wd] >> 16)) +
                             bf2f((unsigned short)(tu[wd] >> 16)) + bb[wd * 2 + 1], 0.f);
            w[wd] = (unsigned int)f2bf(x0) | ((unsigned int)f2bf(x1) << 16);
        }
        int ch2 = ch ^ (px & 7) ^ (((px >> 3) & 1) << 3);
        As[px * 64 + ch2] = make_uint4(w[0], w[1], w[2], w[3]);
    }
    __syncthreads();
    int wv = tid >> 6, lane = tid & 63, r = lane & 15, g = lane >> 4;
    int q0 = wv * 32;
    f32x4 acc[2][2] = {{{0.f,0.f,0.f,0.f},{0.f,0.f,0.f,0.f}},{{0.f,0.f,0.f,0.f},{0.f,0.f,0.f,0.f}}};
    bf16x8 Bb[4][2], Aa[2][2];
#define Q1_LB(slot, it_) { const unsigned short* bp = Bw + (size_t)(q0 + r) * 512 + (it_) * 32 + g * 8; \
    Bb[slot][0] = *(const bf16x8*)bp; Bb[slot][1] = *(const bf16x8*)(bp + 16 * 512); }
#define Q1_LA(slot, it_) { int ch = (it_) * 4 + g; \
    int px0 = r, px1 = 16 + r; \
    Aa[slot][0] = *(const bf16x8*)&As[px0 * 64 + (ch ^ (px0 & 7) ^ (((px0 >> 3) & 1) << 3))]; \
    Aa[slot][1] = *(const bf16x8*)&As[px1 * 64 + (ch ^ (px1 & 7) ^ (((px1 >> 3) & 1) << 3))]; }
    Q1_LB(0, 0); Q1_LB(1, 1); Q1_LB(2, 2); Q1_LA(0, 0);
    #pragma unroll
    for (int it = 0; it < 16; ++it) {
        if (it + 3 < 16) Q1_LB((it + 3) & 3, it + 3);
        if (it + 1 < 16) Q1_LA((it + 1) & 1, it + 1);
        int s = it & 3, sa = it & 1;
        acc[0][0] = MFMA16(Aa[sa][0], Bb[s][0], acc[0][0]);
        acc[0][1] = MFMA16(Aa[sa][0], Bb[s][1], acc[0][1]);
        acc[1][0] = MFMA16(Aa[sa][1], Bb[s][0], acc[1][0]);
        acc[1][1] = MFMA16(Aa[sa][1], Bb[s][1], acc[1][1]);
    }
    float bi0 = bias[q0 + r], bi1 = bias[q0 + 16 + r];
    unsigned short* Pout = P1 + (size_t)b * PSTRIDE;
    #pragma unroll
    for (int mt = 0; mt < 2; ++mt)
        #pragma unroll
        for (int reg = 0; reg < 4; ++reg) {
            int px = mt * 16 + g * 4 + reg;
            if (m0 + px < NVALID) {
                int q = qmap[px];
                int i = q / 100, j = q - i * 100;
                size_t base = (size_t)((i + 1) * PADW + j + 1) * H2C;
                Pout[base + q0 + r]      = f2bf(fmaxf(acc[mt][0][reg] + bi0, 0.f));
                Pout[base + q0 + 16 + r] = f2bf(fmaxf(acc[mt][1][reg] + bi1, 0.f));
            }
        }
}

// ---------- 3x3 conv 128->128, M=64 (2 output rows/block); FQ4: fused q4+sigmoid ----------
template<int FQ4>
__global__ __launch_bounds__(256) void k_c3m2(int in_off, int w_off,
                                              const float* __restrict__ bias,
                                              int out_off,
                                              const float* __restrict__ wq4,
                                              const float* __restrict__ bq4,
                                              float* __restrict__ out) {
    __shared__ uint4 As[2176];                 // 4 rows x 34 px x 16 oct
    const unsigned short* Pin = (const unsigned short*)(g_buf + in_off);
    const unsigned short* wB  = (const unsigned short*)(g_buf + w_off);
    int jt = blockIdx.x, y = blockIdx.y, b = blockIdx.z;
    int i0 = y * 2;
    int j0 = (jt == 3) ? 68 : jt * 32;
    int tid = threadIdx.x;
    const unsigned short* Ab = Pin + (size_t)b * PSTRIDE;
    for (int idx = tid; idx < 2176; idx += 256) {
        int row = idx / 544, rem = idx - row * 544;
        int px = rem >> 4, ch = rem & 15;
        int ch2 = ch ^ (px & 7) ^ (((px >> 3) & 1) << 3);
        As[(row * 34 + px) * 16 + ch2] =
            *(const uint4*)(Ab + (size_t)((i0 + row) * PADW + j0 + px) * H2C + ch * 8);
    }
    __syncthreads();
    int wv = tid >> 6, lane = tid & 63, r = lane & 15, g = lane >> 4;
    int q0 = wv * 32;
    f32x4 acc[2][2][2];
    #pragma unroll
    for (int a = 0; a < 2; ++a)
        #pragma unroll
        for (int m = 0; m < 2; ++m)
            #pragma unroll
            for (int h = 0; h < 2; ++h) acc[a][m][h] = (f32x4){0.f, 0.f, 0.f, 0.f};
    bf16x8 Bb[4][2], Aa[2][4];
#define C2_LB(slot, it_) { int tap = (it_) >> 2, cc = (it_) & 3; \
    const unsigned short* bp = wB + (size_t)(q0 + r) * 1152 + tap * 128 + cc * 32 + g * 8; \
    Bb[slot][0] = *(const bf16x8*)bp; Bb[slot][1] = *(const bf16x8*)(bp + 16 * 1152); }
#define C2_LA(slot, it_) { int tap = (it_) >> 2, cc = (it_) & 3; \
    int ky = tap / 3, kx = tap - ky * 3; int ch = cc * 4 + g; \
    int px0 = r + kx, px1 = 16 + r + kx; \
    Aa[slot][0] = *(const bf16x8*)&As[(ky * 34 + px0) * 16 + (ch ^ (px0 & 7) ^ (((px0 >> 3) & 1) << 3))]; \
    Aa[slot][1] = *(const bf16x8*)&As[(ky * 34 + px1) * 16 + (ch ^ (px1 & 7) ^ (((px1 >> 3) & 1) << 3))]; \
    Aa[slot][2] = *(const bf16x8*)&As[((ky + 1) * 34 + px0) * 16 + (ch ^ (px0 & 7) ^ (((px0 >> 3) & 1) << 3))]; \
    Aa[slot][3] = *(const bf16x8*)&As[((ky + 1) * 34 + px1) * 16 + (ch ^ (px1 & 7) ^ (((px1 >> 3) & 1) << 3))]; }
    C2_LB(0, 0); C2_LB(1, 1); C2_LB(2, 2); C2_LA(0, 0);
    #pragma unroll
    for (int it = 0; it < 36; ++it) {
        if (it + 3 < 36) C2_LB((it + 3) & 3, it + 3);
        if (it + 1 < 36) C2_LA((it + 1) & 1, it + 1);
        int s = it & 3, sa = it & 1;
        acc[0][0][0] = MFMA16(Aa[sa][0], Bb[s][0], acc[0][0][0]);
        acc[0][0][1] = MFMA16(Aa[sa][0], Bb[s][1], acc[0][0][1]);
        acc[0][1][0] = MFMA16(Aa[sa][1], Bb[s][0], acc[0][1][0]);
        acc[0][1][1] = MFMA16(Aa[sa][1], Bb[s][1], acc[0][1][1]);
        acc[1][0][0] = MFMA16(Aa[sa][2], Bb[s][0], acc[1][0][0]);
        acc[1][0][1] = MFMA16(Aa[sa][2], Bb[s][1], acc[1][0][1]);
        acc[1][1][0] = MFMA16(Aa[sa][3], Bb[s][0], acc[1][1][0]);
        acc[1][1][1] = MFMA16(Aa[sa][3], Bb[s][1], acc[1][1][1]);
    }
    float bi0 = bias[q0 + r], bi1 = bias[q0 + 16 + r];
    if constexpr (!FQ4) {
        unsigned short* Ob = (unsigned short*)(g_buf + out_off) + (size_t)b * PSTRIDE;
        #pragma unroll
        for (int orow = 0; orow < 2; ++orow)
            #pragma unroll
            for (int mt = 0; mt < 2; ++mt)
                #pragma unroll
                for (int reg = 0; reg < 4; ++reg) {
                    int j = j0 + mt * 16 + g * 4 + reg;
                    size_t base = (size_t)((i0 + orow + 1) * PADW + j + 1) * H2C;
                    Ob[base + q0 + r]      = f2bf(fmaxf(acc[orow][mt][0][reg] + bi0, 0.f));
                    Ob[base + q0 + 16 + r] = f2bf(fmaxf(acc[orow][mt][1][reg] + bi1, 0.f));
                }
    } else {
        __shared__ float part[4][2][2][32];
        float w40a = wq4[q0 + r],       w40b = wq4[q0 + 16 + r];
        float w41a = wq4[128 + q0 + r], w41b = wq4[128 + q0 + 16 + r];
        #pragma unroll
        for (int orow = 0; orow < 2; ++orow)
            #pragma unroll
            for (int mt = 0; mt < 2; ++mt)
                #pragma unroll
                for (int reg = 0; reg < 4; ++reg) {
                    float x0 = fmaxf(acc[orow][mt][0][reg] + bi0, 0.f);
                    float x1 = fmaxf(acc[orow][mt][1][reg] + bi1, 0.f);
                    float p0 = x0 * w40a + x1 * w40b;
                    float p1 = x0 * w41a + x1 * w41b;
                    #pragma unroll
                    for (int off = 1; off < 16; off <<= 1) {
                        p0 += __shfl_xor(p0, off);
                        p1 += __shfl_xor(p1, off);
                    }
                    if (r == 0) {
                        int px = mt * 16 + g * 4 + reg;
                        part[wv][orow][0][px] = p0;
                        part[wv][orow][1][px] = p1;
                    }
                }
        __syncthreads();
        if (tid < 128) {
            int px = tid & 31, hd = (tid >> 5) & 1, orow = tid >> 6;
            float s = part[0][orow][hd][px] + part[1][orow][hd][px] +
                      part[2][orow][hd][px] + part[3][orow][hd][px] + bq4[hd];
            out[(size_t)(b * 2 + hd) * IJ + (i0 + orow) * 100 + (j0 + px)] =
                1.f / (1.f + expf(-s));
        }
    }
}

extern "C" void kernel_launch(void* const* d_in, const int* in_sizes, int n_in,
                              void* d_out, int out_size, void* d_ws, size_t ws_size,
                              hipStream_t stream) {
    const float* x   = (const float*)d_in[0];
    const float* wb1 = (const float*)d_in[1];  const float* bb1 = (const float*)d_in[2];
    const float* wb2 = (const float*)d_in[3];  const float* bb2 = (const float*)d_in[4];
    const float* ws1 = (const float*)d_in[5];  const float* bs1 = (const float*)d_in[6];
    const float* ws2 = (const float*)d_in[7];  const float* bs2 = (const float*)d_in[8];
    const float* we1 = (const float*)d_in[9];  const float* be1 = (const float*)d_in[10];
    const float* we2 = (const float*)d_in[11]; const float* be2 = (const float*)d_in[12];
    const float* wp  = (const float*)d_in[13]; const float* bp  = (const float*)d_in[14];
    const float* w3d = (const float*)d_in[15]; const float* b3d = (const float*)d_in[16];
    const float* wq1 = (const float*)d_in[17]; const float* bq1 = (const float*)d_in[18];
    const float* wq2 = (const float*)d_in[19]; const float* bq2 = (const float*)d_in[20];
    const float* wq3 = (const float*)d_in[21]; const float* bq3 = (const float*)d_in[22];
    const float* wq4 = (const float*)d_in[23]; const float* bq4 = (const float*)d_in[24];
    float* out = (float*)d_out;

    k_prepw<<<512 + (PREP_IDS + 255) / 256, 256, 0, stream>>>(wq1, wq2, wq3, x, b3d, bq1, w3d);
    k_conv_t<100, 64, 400><<<800, 256, 0, stream>>>(OFF_XT, wb1, bb1, OFF_H1);
    k_conv_t<64, 64, 256><<<800, 256, 0, stream>>>(OFF_H1, wb2, bb2, OFF_H2);
    k_sepf<<<2400, 256, 0, stream>>>(ws1, bs1, we1, be1, wp, bp);
    k_amfh<<<1792 + Q1F_BLKS + 2, 256, 0, stream>>>(ws2, bs2, we2, be2, out);
    k_bm2<<<dim3(20, 16, 4), 256, 0, stream>>>();
    k_q1m<<<dim3((NVALID + 31) / 32, 2), 256, 0, stream>>>(bq1, b3d);
    k_c3m2<0><<<dim3(4, 50, 2), 256, 0, stream>>>(OFF_P1, OFF_WQ2B, bq2, OFF_P2,
                                                  nullptr, nullptr, nullptr);
    k_c3m2<1><<<dim3(4, 50, 2), 256, 0, stream>>>(OFF_P2, OFF_WQ3B, bq3, 0,
                                                  wq4, bq4, out);
}